// Round 1
// baseline (6216.420 us; speedup 1.0000x reference)
//
#include <hip/hip_runtime.h>
#include <hip/hip_bf16.h>

#define N_NODES 50000
#define N_EDGES 800000
#define FIN 92
#define FD 128
#define DE 50
#define NL 3
#define NG 256

typedef short short8 __attribute__((ext_vector_type(8)));
typedef float f32x4 __attribute__((ext_vector_type(4)));

__device__ __forceinline__ short f2bf(float f) {
    unsigned u = __builtin_bit_cast(unsigned, f);
    unsigned r = (u + 0x7FFFu + ((u >> 16) & 1u)) >> 16;
    return (short)r;
}
__device__ __forceinline__ float bf2f(unsigned short b) {
    unsigned u = ((unsigned)b) << 16;
    return __builtin_bit_cast(float, u);
}

// ---------------- bf16-MFMA GEMM: C[M,Nc] = A[M,K] @ B[K,Nc] ----------------
template<int KPAD, int RELU, int OUTBF>
__global__ __launch_bounds__(256) void gemm_kernel(
    const float* __restrict__ A, const float* __restrict__ B,
    void* __restrict__ Cout, int M, int K, int Nc)
{
    __shared__ short Alds[64][KPAD + 8];
    __shared__ short Blds[64][KPAD + 8];   // holds B^T tile: [n][k]
    const int tid = threadIdx.x;
    const int m0 = blockIdx.x * 64;
    const int n0 = blockIdx.y * 64;

    for (int i = tid; i < 64 * KPAD; i += 256) {
        int r = i / KPAD, k = i - r * KPAD;
        int row = m0 + r;
        float v = (row < M && k < K) ? A[(size_t)row * K + k] : 0.f;
        Alds[r][k] = f2bf(v);
    }
    for (int i = tid; i < 64 * KPAD; i += 256) {
        int n = i & 63, k = i >> 6;
        float v = (k < K) ? B[(size_t)k * Nc + n0 + n] : 0.f;
        Blds[n][k] = f2bf(v);
    }
    __syncthreads();

    const int wv = tid >> 6, lane = tid & 63;
    const int lr = lane & 15, lk = (lane >> 4) * 8;
    f32x4 acc[4];
#pragma unroll
    for (int i = 0; i < 4; ++i) acc[i] = (f32x4)0.f;

    for (int k0 = 0; k0 < KPAD; k0 += 32) {
        short8 a = *(const short8*)&Alds[wv * 16 + lr][k0 + lk];
#pragma unroll
        for (int nf = 0; nf < 4; ++nf) {
            short8 b = *(const short8*)&Blds[nf * 16 + lr][k0 + lk];
            acc[nf] = __builtin_amdgcn_mfma_f32_16x16x32_bf16(a, b, acc[nf], 0, 0, 0);
        }
    }
#pragma unroll
    for (int nf = 0; nf < 4; ++nf) {
#pragma unroll
        for (int r = 0; r < 4; ++r) {
            int row = m0 + wv * 16 + (lane >> 4) * 4 + r;
            int col = n0 + nf * 16 + lr;
            if (row < M) {
                float v = acc[nf][r];
                if (RELU) v = fmaxf(v, 0.f);
                if (OUTBF) ((unsigned short*)Cout)[(size_t)row * Nc + col] = (unsigned short)f2bf(v);
                else       ((float*)Cout)[(size_t)row * Nc + col] = v;
            }
        }
    }
}

// -------- build concatenated per-layer projection weights: Bcat[l][128][512] --------
__global__ __launch_bounds__(256) void build_bcat_kernel(
    const float* __restrict__ wf, const float* __restrict__ wsw, float* __restrict__ Bcat)
{
    int i = blockIdx.x * 256 + threadIdx.x;
    if (i >= NL * FD * 512) return;
    int l = i / (FD * 512);
    int r = i - l * FD * 512;
    int k = r >> 9, j = r & 511;
    const float* Wm = (j < 256) ? wf : wsw;
    int jj = j & 255;
    int krow = (jj < FD) ? k : (FD + k);
    int col = jj & 127;
    Bcat[i] = Wm[((size_t)l * 306 + krow) * FD + col];
}

// -------- fused message kernel: edge-proj + gather + gate + scatter-add --------
__global__ __launch_bounds__(256) void msg_kernel(
    const float* __restrict__ P,          // [N][512] fp32: dstF|srcF|dstS|srcS
    const float* __restrict__ edge_attr,  // [E][50]
    const float* __restrict__ wfl,        // wf + l*306*128 (edge rows at 256..305)
    const float* __restrict__ wsl,
    const float* __restrict__ bfl, const float* __restrict__ bsl,
    const int* __restrict__ srcIdx, const int* __restrict__ dstIdx,
    float* __restrict__ agg)
{
    __shared__ float wf_lds[52][128];
    __shared__ float ws_lds[52][128];
    __shared__ float ea_lds[32][52];
    const int tid = threadIdx.x;
    const int e0 = blockIdx.x * 32;

    for (int i = tid; i < 52 * 128; i += 256) {
        int k = i >> 7, f = i & 127;
        wf_lds[k][f] = (k < DE) ? wfl[(256 + k) * FD + f] : 0.f;
        ws_lds[k][f] = (k < DE) ? wsl[(256 + k) * FD + f] : 0.f;
    }
    for (int i = tid; i < 32 * 52; i += 256) {
        int e = i / 52, k = i - e * 52;
        ea_lds[e][k] = (k < DE) ? edge_attr[(size_t)(e0 + e) * DE + k] : 0.f;
    }
    __syncthreads();

    const int f = tid & 127;
    const int slot = tid >> 7;
    const float bfv = bfl[f], bsv = bsl[f];

    for (int it = 0; it < 4; ++it) {
        const int eb = it * 8 + slot * 4;   // local edge base (4 edges per thread)
        const int ge = e0 + eb;
        int d[4], s[4];
#pragma unroll
        for (int j = 0; j < 4; ++j) { d[j] = dstIdx[ge + j]; s[j] = srcIdx[ge + j]; }
        // issue gathers early; they overlap the k-loop below
        float pdf[4], psf[4], pds[4], pss[4];
#pragma unroll
        for (int j = 0; j < 4; ++j) {
            const float* pd = P + (size_t)d[j] * 512;
            const float* psrc = P + (size_t)s[j] * 512;
            pdf[j] = pd[f];
            psf[j] = psrc[128 + f];
            pds[j] = pd[256 + f];
            pss[j] = psrc[384 + f];
        }
        float accf[4] = {0.f, 0.f, 0.f, 0.f};
        float accs[4] = {0.f, 0.f, 0.f, 0.f};
#pragma unroll
        for (int c = 0; c < 13; ++c) {
            f32x4 e4[4];
#pragma unroll
            for (int j = 0; j < 4; ++j) e4[j] = *(const f32x4*)&ea_lds[eb + j][c * 4];
#pragma unroll
            for (int kk = 0; kk < 4; ++kk) {
                float wfk = wf_lds[c * 4 + kk][f];
                float wsk = ws_lds[c * 4 + kk][f];
#pragma unroll
                for (int j = 0; j < 4; ++j) {
                    accf[j] = fmaf(e4[j][kk], wfk, accf[j]);
                    accs[j] = fmaf(e4[j][kk], wsk, accs[j]);
                }
            }
        }
#pragma unroll
        for (int j = 0; j < 4; ++j) {
            float pf = accf[j] + bfv + pdf[j] + psf[j];
            float ps = accs[j] + bsv + pds[j] + pss[j];
            float sig = 1.f / (1.f + __expf(-pf));
            float sp = fmaxf(ps, 0.f) + log1pf(__expf(-fabsf(ps)));
            unsafeAtomicAdd(&agg[(size_t)d[j] * FD + f], sig * sp);
        }
    }
}

// -------- BatchNorm stats over N rows --------
__global__ __launch_bounds__(256) void bn_stats_kernel(
    const float* __restrict__ agg, float* __restrict__ stats)
{
    const int tid = threadIdx.x;
    const int f = tid & 127;
    float s = 0.f, sq = 0.f;
    for (int row = blockIdx.x * 2 + (tid >> 7); row < N_NODES; row += gridDim.x * 2) {
        float v = agg[(size_t)row * FD + f];
        s += v; sq += v * v;
    }
    unsafeAtomicAdd(&stats[f], s);
    unsafeAtomicAdd(&stats[128 + f], sq);
}

// -------- h = relu(h + BN(agg)); atomicMax into per-graph max --------
__global__ __launch_bounds__(256) void bn_update_kernel(
    float* __restrict__ h, const float* __restrict__ agg,
    const float* __restrict__ stats, const float* __restrict__ g,
    const float* __restrict__ b, const int* __restrict__ batch,
    float* __restrict__ gmax)
{
    const int tid = threadIdx.x;
    const int row = blockIdx.x * 2 + (tid >> 7);
    if (row >= N_NODES) return;
    const int f = tid & 127;
    const float inv = 1.f / (float)N_NODES;
    float mu = stats[f] * inv;
    float var = stats[128 + f] * inv - mu * mu;
    float rs = rsqrtf(var + 1e-5f);
    size_t idx = (size_t)row * FD + f;
    float v = h[idx] + (agg[idx] - mu) * rs * g[f] + b[f];
    v = fmaxf(v, 0.f);
    h[idx] = v;
    atomicMax((unsigned*)&gmax[batch[row] * FD + f], __float_as_uint(v));
}

__global__ __launch_bounds__(256) void gf_acc_kernel(float* __restrict__ gf, const float* __restrict__ gmax)
{
    int i = blockIdx.x * 256 + threadIdx.x;
    gf[i] += gmax[i];
}

// -------- head --------
__global__ __launch_bounds__(128) void head_y_kernel(
    const float* __restrict__ gf, const float* __restrict__ w1,
    const float* __restrict__ b1, float* __restrict__ y)
{
    __shared__ float row[128];
    int g = blockIdx.x, j = threadIdx.x;
    row[j] = gf[g * FD + j];
    __syncthreads();
    float acc = b1[j];
    for (int k = 0; k < FD; ++k) acc = fmaf(row[k], w1[k * FD + j], acc);
    y[g * FD + j] = acc;
}

__global__ __launch_bounds__(128) void head_stats_kernel(
    const float* __restrict__ y, float* __restrict__ hstat)
{
    int f = threadIdx.x;
    float s = 0.f, sq = 0.f;
    for (int g = 0; g < NG; ++g) { float v = y[g * FD + f]; s += v; sq += v * v; }
    float mu = s / (float)NG;
    float var = sq / (float)NG - mu * mu;
    hstat[f] = mu;
    hstat[128 + f] = rsqrtf(var + 1e-5f);
}

__global__ __launch_bounds__(128) void head_out_kernel(
    const float* __restrict__ y, const float* __restrict__ hstat,
    const float* __restrict__ bng, const float* __restrict__ bnb,
    const float* __restrict__ w2, const float* __restrict__ b2,
    float* __restrict__ out)
{
    __shared__ float part[2];
    int g = blockIdx.x, f = threadIdx.x;
    float v = (y[g * FD + f] - hstat[f]) * hstat[128 + f] * bng[f] + bnb[f];
    v = fmaxf(v, 0.f) * w2[f];
    for (int o = 32; o > 0; o >>= 1) v += __shfl_down(v, o);
    if ((f & 63) == 0) part[f >> 6] = v;
    __syncthreads();
    if (f == 0) out[g] = part[0] + part[1] + b2[0];
}

extern "C" void kernel_launch(void* const* d_in, const int* in_sizes, int n_in,
                              void* d_out, int out_size, void* d_ws, size_t ws_size,
                              hipStream_t stream)
{
    const float* x        = (const float*)d_in[0];
    const float* edge_attr= (const float*)d_in[1];
    const float* w_emb0   = (const float*)d_in[2];
    const float* w_emb1   = (const float*)d_in[3];
    const float* wf       = (const float*)d_in[4];
    const float* bf       = (const float*)d_in[5];
    const float* wsw      = (const float*)d_in[6];
    const float* bs       = (const float*)d_in[7];
    const float* bn_g     = (const float*)d_in[8];
    const float* bn_b     = (const float*)d_in[9];
    const float* w1       = (const float*)d_in[10];
    const float* b1       = (const float*)d_in[11];
    const float* bng      = (const float*)d_in[12];
    const float* bnb      = (const float*)d_in[13];
    const float* w2       = (const float*)d_in[14];
    const float* b2       = (const float*)d_in[15];
    const int*   eidx     = (const int*)d_in[16];   // [2][E]: row0=src, row1=dst
    const int*   batch    = (const int*)d_in[17];

    char* base = (char*)d_ws;
    size_t off = 0;
    auto alloc = [&](size_t bytes) -> void* {
        void* p = base + off;
        off += (bytes + 255) & ~(size_t)255;
        return p;
    };
    float*          h     = (float*)alloc((size_t)N_NODES * FD * 4);
    float*          P     = (float*)alloc((size_t)N_NODES * 512 * 4);
    float*          agg   = (float*)alloc((size_t)N_NODES * FD * 4);   // also embed tmp
    float*          Bcat  = (float*)alloc((size_t)NL * FD * 512 * 4);
    float*          stats = (float*)alloc(256 * 4);
    float*          gmax  = (float*)alloc((size_t)NG * FD * 4);
    float*          gf    = (float*)alloc((size_t)NG * FD * 4);
    float*          y     = (float*)alloc((size_t)NG * FD * 4);
    float*          hstat = (float*)alloc(256 * 4);

    const int MB = (N_NODES + 63) / 64;  // 782

    build_bcat_kernel<<<(NL * FD * 512 + 255) / 256, 256, 0, stream>>>(wf, wsw, Bcat);

    // embedding MLP: t0 = relu(x@w_emb0); h = t0@w_emb1   (t0 uses agg buffer)
    gemm_kernel<96, 1, 0><<<dim3(MB, 2), 256, 0, stream>>>(x, w_emb0, agg, N_NODES, FIN, FD);
    gemm_kernel<128, 0, 0><<<dim3(MB, 2), 256, 0, stream>>>(agg, w_emb1, h, N_NODES, FD, FD);

    hipMemsetAsync(gf, 0, (size_t)NG * FD * 4, stream);

    for (int l = 0; l < NL; ++l) {
        hipMemsetAsync(agg, 0, (size_t)N_NODES * FD * 4, stream);
        hipMemsetAsync(stats, 0, 256 * 4, stream);
        hipMemsetAsync(gmax, 0, (size_t)NG * FD * 4, stream);

        gemm_kernel<128, 0, 0><<<dim3(MB, 8), 256, 0, stream>>>(
            h, Bcat + (size_t)l * FD * 512, P, N_NODES, FD, 512);

        msg_kernel<<<N_EDGES / 32, 256, 0, stream>>>(
            P, edge_attr, wf + (size_t)l * 306 * FD, wsw + (size_t)l * 306 * FD,
            bf + l * FD, bs + l * FD, eidx, eidx + N_EDGES, agg);

        bn_stats_kernel<<<512, 256, 0, stream>>>(agg, stats);
        bn_update_kernel<<<(N_NODES + 1) / 2, 256, 0, stream>>>(
            h, agg, stats, bn_g + l * FD, bn_b + l * FD, batch, gmax);
        gf_acc_kernel<<<(NG * FD) / 256, 256, 0, stream>>>(gf, gmax);
    }

    head_y_kernel<<<NG, 128, 0, stream>>>(gf, w1, b1, y);
    head_stats_kernel<<<1, 128, 0, stream>>>(y, hstat);
    head_out_kernel<<<NG, 128, 0, stream>>>(y, hstat, bng, bnb, w2, b2, (float*)d_out);
}

// Round 2
// 3402.206 us; speedup vs baseline: 1.8272x; 1.8272x over previous
//
#include <hip/hip_runtime.h>
#include <hip/hip_bf16.h>

#define N_NODES 50000
#define N_EDGES 800000
#define FIN 92
#define FD 128
#define DE 50
#define NL 3
#define NG 256

typedef short short8 __attribute__((ext_vector_type(8)));
typedef float f32x4 __attribute__((ext_vector_type(4)));

__device__ __forceinline__ short f2bf(float f) {
    unsigned u = __builtin_bit_cast(unsigned, f);
    unsigned r = (u + 0x7FFFu + ((u >> 16) & 1u)) >> 16;
    return (short)r;
}
__device__ __forceinline__ float bf2f(unsigned short b) {
    unsigned u = ((unsigned)b) << 16;
    return __builtin_bit_cast(float, u);
}

// ---------------- bf16-MFMA GEMM: C[M,Nc] = A[M,K] @ B[K,Nc] (+bias) ----------------
// grid: (n-blocks, m-blocks) -- n fastest for A-tile L2 reuse
template<int KPAD, int RELU, int OUTBF, int BIAS>
__global__ __launch_bounds__(256) void gemm_kernel(
    const float* __restrict__ A, const float* __restrict__ B,
    void* __restrict__ Cout, const float* __restrict__ bias,
    int M, int K, int Nc)
{
    __shared__ short Alds[64][KPAD + 8];
    __shared__ short Blds[64][KPAD + 8];   // holds B^T tile: [n][k]
    const int tid = threadIdx.x;
    const int m0 = blockIdx.y * 64;
    const int n0 = blockIdx.x * 64;

    for (int i = tid; i < 64 * KPAD; i += 256) {
        int r = i / KPAD, k = i - r * KPAD;
        int row = m0 + r;
        float v = (row < M && k < K) ? A[(size_t)row * K + k] : 0.f;
        Alds[r][k] = f2bf(v);
    }
    for (int i = tid; i < 64 * KPAD; i += 256) {
        int n = i & 63, k = i >> 6;
        float v = (k < K) ? B[(size_t)k * Nc + n0 + n] : 0.f;
        Blds[n][k] = f2bf(v);
    }
    __syncthreads();

    const int wv = tid >> 6, lane = tid & 63;
    const int lr = lane & 15, lk = (lane >> 4) * 8;
    f32x4 acc[4];
#pragma unroll
    for (int i = 0; i < 4; ++i) acc[i] = (f32x4)0.f;

    for (int k0 = 0; k0 < KPAD; k0 += 32) {
        short8 a = *(const short8*)&Alds[wv * 16 + lr][k0 + lk];
#pragma unroll
        for (int nf = 0; nf < 4; ++nf) {
            short8 b = *(const short8*)&Blds[nf * 16 + lr][k0 + lk];
            acc[nf] = __builtin_amdgcn_mfma_f32_16x16x32_bf16(a, b, acc[nf], 0, 0, 0);
        }
    }
#pragma unroll
    for (int nf = 0; nf < 4; ++nf) {
#pragma unroll
        for (int r = 0; r < 4; ++r) {
            int row = m0 + wv * 16 + (lane >> 4) * 4 + r;
            int col = n0 + nf * 16 + lr;
            if (row < M) {
                float v = acc[nf][r];
                if (BIAS) v += bias[col];
                if (RELU) v = fmaxf(v, 0.f);
                if (OUTBF) ((unsigned short*)Cout)[(size_t)row * Nc + col] = (unsigned short)f2bf(v);
                else       ((float*)Cout)[(size_t)row * Nc + col] = v;
            }
        }
    }
}

// -------- build concatenated per-layer node-projection weights: Bcat[l][128][512] --------
__global__ __launch_bounds__(256) void build_bcat_kernel(
    const float* __restrict__ wf, const float* __restrict__ wsw, float* __restrict__ Bcat)
{
    int i = blockIdx.x * 256 + threadIdx.x;
    if (i >= NL * FD * 512) return;
    int l = i / (FD * 512);
    int r = i - l * FD * 512;
    int k = r >> 9, j = r & 511;
    const float* Wm = (j < 256) ? wf : wsw;
    int jj = j & 255;
    int krow = (jj < FD) ? k : (FD + k);
    int col = jj & 127;
    Bcat[i] = Wm[((size_t)l * 306 + krow) * FD + col];
}

// -------- build edge-projection weights Wecat[l][50][256] and bias bcat[l][256] --------
__global__ __launch_bounds__(256) void build_wecat_kernel(
    const float* __restrict__ wf, const float* __restrict__ wsw,
    const float* __restrict__ bf, const float* __restrict__ bs,
    float* __restrict__ Wecat, float* __restrict__ bcat)
{
    int i = blockIdx.x * 256 + threadIdx.x;
    if (i < NL * DE * 256) {
        int l = i / (DE * 256);
        int r = i - l * DE * 256;
        int k = r >> 8, j = r & 255;
        const float* W = (j < 128) ? wf : wsw;
        Wecat[i] = W[((size_t)l * 306 + 256 + k) * FD + (j & 127)];
    }
    if (i < NL * 256) {
        int l = i >> 8, j = i & 255;
        bcat[i] = (j < 128) ? bf[l * FD + j] : bs[l * FD + (j & 127)];
    }
}

// -------- slim message kernel: gather + gate + scatter-add --------
// Eproj: [nE][256] bf16 (bias already added): cols 0..127 = filter pre-act edge part,
//        128..255 = soft pre-act edge part
#define EPB 16
__global__ __launch_bounds__(256) void msg2_kernel(
    const float* __restrict__ P,              // [N][512]: dstF|srcF|dstS|srcS
    const unsigned short* __restrict__ Eproj, // [nE][256] bf16
    const int* __restrict__ srcIdx, const int* __restrict__ dstIdx,
    float* __restrict__ agg, int nE)
{
    const int tid = threadIdx.x;
    const int f = tid & 127;
    const int slot = tid >> 7;
    int e = blockIdx.x * EPB + slot;
#pragma unroll
    for (int i = 0; i < EPB / 2; ++i, e += 2) {
        if (e < nE) {
            int d = dstIdx[e], s = srcIdx[e];
            const float* pd = P + (size_t)d * 512;
            const float* ps_ = P + (size_t)s * 512;
            float pf = bf2f(Eproj[(size_t)e * 256 + f]) + pd[f] + ps_[128 + f];
            float ps = bf2f(Eproj[(size_t)e * 256 + 128 + f]) + pd[256 + f] + ps_[384 + f];
            float sig = 1.f / (1.f + __expf(-pf));
            float t = __expf(-fabsf(ps));
            float sp = fmaxf(ps, 0.f) + __logf(1.f + t);
            unsafeAtomicAdd(&agg[(size_t)d * FD + f], sig * sp);
        }
    }
}

// -------- BatchNorm stats over N rows --------
__global__ __launch_bounds__(256) void bn_stats_kernel(
    const float* __restrict__ agg, float* __restrict__ stats)
{
    const int tid = threadIdx.x;
    const int f = tid & 127;
    float s = 0.f, sq = 0.f;
    for (int row = blockIdx.x * 2 + (tid >> 7); row < N_NODES; row += gridDim.x * 2) {
        float v = agg[(size_t)row * FD + f];
        s += v; sq += v * v;
    }
    unsafeAtomicAdd(&stats[f], s);
    unsafeAtomicAdd(&stats[128 + f], sq);
}

// -------- h = relu(h + BN(agg)); atomicMax into per-graph max --------
__global__ __launch_bounds__(256) void bn_update_kernel(
    float* __restrict__ h, const float* __restrict__ agg,
    const float* __restrict__ stats, const float* __restrict__ g,
    const float* __restrict__ b, const int* __restrict__ batch,
    float* __restrict__ gmax)
{
    const int tid = threadIdx.x;
    const int row = blockIdx.x * 2 + (tid >> 7);
    if (row >= N_NODES) return;
    const int f = tid & 127;
    const float inv = 1.f / (float)N_NODES;
    float mu = stats[f] * inv;
    float var = stats[128 + f] * inv - mu * mu;
    float rs = rsqrtf(var + 1e-5f);
    size_t idx = (size_t)row * FD + f;
    float v = h[idx] + (agg[idx] - mu) * rs * g[f] + b[f];
    v = fmaxf(v, 0.f);
    h[idx] = v;
    atomicMax((unsigned*)&gmax[batch[row] * FD + f], __float_as_uint(v));
}

__global__ __launch_bounds__(256) void gf_acc_kernel(float* __restrict__ gf, const float* __restrict__ gmax)
{
    int i = blockIdx.x * 256 + threadIdx.x;
    gf[i] += gmax[i];
}

// -------- head --------
__global__ __launch_bounds__(128) void head_y_kernel(
    const float* __restrict__ gf, const float* __restrict__ w1,
    const float* __restrict__ b1, float* __restrict__ y)
{
    __shared__ float row[128];
    int g = blockIdx.x, j = threadIdx.x;
    row[j] = gf[g * FD + j];
    __syncthreads();
    float acc = b1[j];
    for (int k = 0; k < FD; ++k) acc = fmaf(row[k], w1[k * FD + j], acc);
    y[g * FD + j] = acc;
}

__global__ __launch_bounds__(128) void head_stats_kernel(
    const float* __restrict__ y, float* __restrict__ hstat)
{
    int f = threadIdx.x;
    float s = 0.f, sq = 0.f;
    for (int g = 0; g < NG; ++g) { float v = y[g * FD + f]; s += v; sq += v * v; }
    float mu = s / (float)NG;
    float var = sq / (float)NG - mu * mu;
    hstat[f] = mu;
    hstat[128 + f] = rsqrtf(var + 1e-5f);
}

__global__ __launch_bounds__(128) void head_out_kernel(
    const float* __restrict__ y, const float* __restrict__ hstat,
    const float* __restrict__ bng, const float* __restrict__ bnb,
    const float* __restrict__ w2, const float* __restrict__ b2,
    float* __restrict__ out)
{
    __shared__ float part[2];
    int g = blockIdx.x, f = threadIdx.x;
    float v = (y[g * FD + f] - hstat[f]) * hstat[128 + f] * bng[f] + bnb[f];
    v = fmaxf(v, 0.f) * w2[f];
    for (int o = 32; o > 0; o >>= 1) v += __shfl_down(v, o);
    if ((f & 63) == 0) part[f >> 6] = v;
    __syncthreads();
    if (f == 0) out[g] = part[0] + part[1] + b2[0];
}

extern "C" void kernel_launch(void* const* d_in, const int* in_sizes, int n_in,
                              void* d_out, int out_size, void* d_ws, size_t ws_size,
                              hipStream_t stream)
{
    const float* x        = (const float*)d_in[0];
    const float* edge_attr= (const float*)d_in[1];
    const float* w_emb0   = (const float*)d_in[2];
    const float* w_emb1   = (const float*)d_in[3];
    const float* wf       = (const float*)d_in[4];
    const float* bf       = (const float*)d_in[5];
    const float* wsw      = (const float*)d_in[6];
    const float* bs       = (const float*)d_in[7];
    const float* bn_g     = (const float*)d_in[8];
    const float* bn_b     = (const float*)d_in[9];
    const float* w1       = (const float*)d_in[10];
    const float* b1       = (const float*)d_in[11];
    const float* bng      = (const float*)d_in[12];
    const float* bnb      = (const float*)d_in[13];
    const float* w2       = (const float*)d_in[14];
    const float* b2       = (const float*)d_in[15];
    const int*   eidx     = (const int*)d_in[16];   // [2][E]: row0=src, row1=dst
    const int*   batch    = (const int*)d_in[17];

    char* base = (char*)d_ws;
    size_t off = 0;
    auto alloc = [&](size_t bytes) -> void* {
        void* p = base + off;
        off += (bytes + 255) & ~(size_t)255;
        return p;
    };
    float*          h     = (float*)alloc((size_t)N_NODES * FD * 4);
    float*          P     = (float*)alloc((size_t)N_NODES * 512 * 4);
    float*          agg   = (float*)alloc((size_t)N_NODES * FD * 4);   // also embed tmp
    float*          Bcat  = (float*)alloc((size_t)NL * FD * 512 * 4);
    float*          Wecat = (float*)alloc((size_t)NL * DE * 256 * 4);
    float*          bcat  = (float*)alloc((size_t)NL * 256 * 4);
    float*          stats = (float*)alloc(256 * 4);
    float*          gmax  = (float*)alloc((size_t)NG * FD * 4);
    float*          gf    = (float*)alloc((size_t)NG * FD * 4);
    float*          y     = (float*)alloc((size_t)NG * FD * 4);
    float*          hstat = (float*)alloc(256 * 4);

    // adaptive Eproj chunk buffer (bf16, [chunkE][256]): use what's left of ws
    size_t remain = (ws_size > off) ? ws_size - off : 0;
    int chunkE = 262144;
    while ((size_t)chunkE * 512 > remain && chunkE > 8192) chunkE >>= 1;
    unsigned short* Echunk = (unsigned short*)alloc((size_t)chunkE * 512);

    const int MB = (N_NODES + 63) / 64;  // 782

    build_bcat_kernel<<<(NL * FD * 512 + 255) / 256, 256, 0, stream>>>(wf, wsw, Bcat);
    build_wecat_kernel<<<(NL * DE * 256 + 255) / 256, 256, 0, stream>>>(wf, wsw, bf, bs, Wecat, bcat);

    // embedding MLP: t0 = relu(x@w_emb0); h = t0@w_emb1   (t0 uses agg buffer)
    gemm_kernel<96, 1, 0, 0><<<dim3(2, MB), 256, 0, stream>>>(x, w_emb0, agg, nullptr, N_NODES, FIN, FD);
    gemm_kernel<128, 0, 0, 0><<<dim3(2, MB), 256, 0, stream>>>(agg, w_emb1, h, nullptr, N_NODES, FD, FD);

    hipMemsetAsync(gf, 0, (size_t)NG * FD * 4, stream);

    for (int l = 0; l < NL; ++l) {
        hipMemsetAsync(agg, 0, (size_t)N_NODES * FD * 4, stream);
        hipMemsetAsync(stats, 0, 256 * 4, stream);
        hipMemsetAsync(gmax, 0, (size_t)NG * FD * 4, stream);

        gemm_kernel<128, 0, 0, 0><<<dim3(8, MB), 256, 0, stream>>>(
            h, Bcat + (size_t)l * FD * 512, P, nullptr, N_NODES, FD, 512);

        for (int e0 = 0; e0 < N_EDGES; e0 += chunkE) {
            int nE = (N_EDGES - e0 < chunkE) ? (N_EDGES - e0) : chunkE;
            int mblk = (nE + 63) / 64;
            gemm_kernel<64, 0, 1, 1><<<dim3(4, mblk), 256, 0, stream>>>(
                edge_attr + (size_t)e0 * DE, Wecat + (size_t)l * DE * 256,
                Echunk, bcat + (size_t)l * 256, nE, DE, 256);
            msg2_kernel<<<(nE + EPB - 1) / EPB, 256, 0, stream>>>(
                P, Echunk, eidx + e0, eidx + N_EDGES + e0, agg, nE);
        }

        bn_stats_kernel<<<512, 256, 0, stream>>>(agg, stats);
        bn_update_kernel<<<(N_NODES + 1) / 2, 256, 0, stream>>>(
            h, agg, stats, bn_g + l * FD, bn_b + l * FD, batch, gmax);
        gf_acc_kernel<<<(NG * FD) / 256, 256, 0, stream>>>(gf, gmax);
    }

    head_y_kernel<<<NG, 128, 0, stream>>>(gf, w1, b1, y);
    head_stats_kernel<<<1, 128, 0, stream>>>(y, hstat);
    head_out_kernel<<<NG, 128, 0, stream>>>(y, hstat, bng, bnb, w2, b2, (float*)d_out);
}

// Round 3
// 2734.994 us; speedup vs baseline: 2.2729x; 1.2440x over previous
//
#include <hip/hip_runtime.h>
#include <hip/hip_bf16.h>

#define N_NODES 50000
#define N_EDGES 800000
#define FIN 92
#define FD 128
#define DE 50
#define NL 3
#define NG 256

typedef short short8 __attribute__((ext_vector_type(8)));
typedef float f32x4 __attribute__((ext_vector_type(4)));

__device__ __forceinline__ short f2bf(float f) {
    unsigned u = __builtin_bit_cast(unsigned, f);
    unsigned r = (u + 0x7FFFu + ((u >> 16) & 1u)) >> 16;
    return (short)r;
}
__device__ __forceinline__ float bf2f(unsigned short b) {
    unsigned u = ((unsigned)b) << 16;
    return __builtin_bit_cast(float, u);
}

// ---------------- bf16-MFMA GEMM: C[M,Nc] = A[M,K] @ B[K,Nc] ----------------
// grid: (n-blocks, m-blocks)
template<int KPAD, int RELU, int OUTBF>
__global__ __launch_bounds__(256) void gemm_kernel(
    const float* __restrict__ A, const float* __restrict__ B,
    void* __restrict__ Cout, int M, int K, int Nc)
{
    __shared__ short Alds[64][KPAD + 8];
    __shared__ short Blds[64][KPAD + 8];   // holds B^T tile: [n][k]
    const int tid = threadIdx.x;
    const int m0 = blockIdx.y * 64;
    const int n0 = blockIdx.x * 64;

    for (int i = tid; i < 64 * KPAD; i += 256) {
        int r = i / KPAD, k = i - r * KPAD;
        int row = m0 + r;
        float v = (row < M && k < K) ? A[(size_t)row * K + k] : 0.f;
        Alds[r][k] = f2bf(v);
    }
    for (int i = tid; i < 64 * KPAD; i += 256) {
        int n = i & 63, k = i >> 6;
        float v = (k < K) ? B[(size_t)k * Nc + n0 + n] : 0.f;
        Blds[n][k] = f2bf(v);
    }
    __syncthreads();

    const int wv = tid >> 6, lane = tid & 63;
    const int lr = lane & 15, lk = (lane >> 4) * 8;
    f32x4 acc[4];
#pragma unroll
    for (int i = 0; i < 4; ++i) acc[i] = (f32x4)0.f;

    for (int k0 = 0; k0 < KPAD; k0 += 32) {
        short8 a = *(const short8*)&Alds[wv * 16 + lr][k0 + lk];
#pragma unroll
        for (int nf = 0; nf < 4; ++nf) {
            short8 b = *(const short8*)&Blds[nf * 16 + lr][k0 + lk];
            acc[nf] = __builtin_amdgcn_mfma_f32_16x16x32_bf16(a, b, acc[nf], 0, 0, 0);
        }
    }
#pragma unroll
    for (int nf = 0; nf < 4; ++nf) {
#pragma unroll
        for (int r = 0; r < 4; ++r) {
            int row = m0 + wv * 16 + (lane >> 4) * 4 + r;
            int col = n0 + nf * 16 + lr;
            if (row < M) {
                float v = acc[nf][r];
                if (RELU) v = fmaxf(v, 0.f);
                if (OUTBF) ((unsigned short*)Cout)[(size_t)row * Nc + col] = (unsigned short)f2bf(v);
                else       ((float*)Cout)[(size_t)row * Nc + col] = v;
            }
        }
    }
}

// -------- build concatenated per-layer node-projection weights: Bcat[l][128][512] --------
__global__ __launch_bounds__(256) void build_bcat_kernel(
    const float* __restrict__ wf, const float* __restrict__ wsw, float* __restrict__ Bcat)
{
    int i = blockIdx.x * 256 + threadIdx.x;
    if (i >= NL * FD * 512) return;
    int l = i / (FD * 512);
    int r = i - l * FD * 512;
    int k = r >> 9, j = r & 511;
    const float* Wm = (j < 256) ? wf : wsw;
    int jj = j & 255;
    int krow = (jj < FD) ? k : (FD + k);
    int col = jj & 127;
    Bcat[i] = Wm[((size_t)l * 306 + krow) * FD + col];
}

// -------- build transposed bf16 edge-proj weights WecatT[l][256][64] + bias bcat[l][256] ----
__global__ __launch_bounds__(256) void build_wecat_kernel(
    const float* __restrict__ wf, const float* __restrict__ wsw,
    const float* __restrict__ bf, const float* __restrict__ bs,
    unsigned short* __restrict__ WecatT, float* __restrict__ bcat)
{
    int i = blockIdx.x * 256 + threadIdx.x;
    if (i < NL * 256 * 64) {
        int l = i / (256 * 64);
        int r = i - l * 256 * 64;
        int col = r >> 6, k = r & 63;
        float v = 0.f;
        if (k < DE) {
            const float* W = (col < 128) ? wf : wsw;
            v = W[((size_t)l * 306 + 256 + k) * FD + (col & 127)];
        }
        WecatT[i] = (unsigned short)f2bf(v);
    }
    if (i < NL * 256) {
        int l = i >> 8, j = i & 255;
        bcat[i] = (j < 128) ? bf[l * FD + j] : bs[l * FD + (j & 127)];
    }
}

// -------- edge_attr -> bf16 padded [E][64] (once) --------
__global__ __launch_bounds__(256) void ea2bf_kernel(
    const float* __restrict__ ea, unsigned short* __restrict__ out)
{
    int i = blockIdx.x * 256 + threadIdx.x;
    if (i >= N_EDGES * 64) return;
    int e = i >> 6, k = i & 63;
    out[i] = (k < DE) ? (unsigned short)f2bf(ea[(size_t)e * DE + k]) : 0;
}

// -------- fused MFMA message kernel: edge-proj (MFMA) + gather + gate + scatter-add ------
// Consumes MFMA accumulator directly in fragment layout:
//   edge = blk*64 + w*16 + (lane>>4)*4 + r, col = nf*16 + (lane&15)
//   filter pre-act = acc[nf], soft pre-act = acc[nf+8]  (same lane, same edge/col)
__global__ __launch_bounds__(256) void msg3_kernel(
    const unsigned short* __restrict__ Pbf,     // [N][512] bf16: dstF|srcF|dstS|srcS
    const unsigned short* __restrict__ eabf,    // [E][64] bf16 padded
    const unsigned short* __restrict__ WecatT,  // [256][64] bf16 (layer offset applied)
    const float* __restrict__ bcat,             // [256]   (layer offset applied)
    const int* __restrict__ srcIdx, const int* __restrict__ dstIdx,
    float* __restrict__ agg)
{
    __shared__ unsigned short Wl[256][72];  // [col][k], pad 72 (rows 144B, 16B-aligned)
    __shared__ unsigned short Al[64][72];   // [edge][k]
    const int tid = threadIdx.x;
    const int e0 = blockIdx.x * 64;

    for (int i = tid; i < 2048; i += 256) {          // 256 rows x 8 chunks of 8 shorts
        int rrow = i >> 3, seg = i & 7;
        *(short8*)&Wl[rrow][seg * 8] = *(const short8*)&WecatT[rrow * 64 + seg * 8];
    }
    for (int i = tid; i < 512; i += 256) {           // 64 rows x 8 chunks
        int rrow = i >> 3, seg = i & 7;
        *(short8*)&Al[rrow][seg * 8] = *(const short8*)&eabf[(size_t)(e0 + rrow) * 64 + seg * 8];
    }
    __syncthreads();

    const int w = tid >> 6, lane = tid & 63;
    const int lr = lane & 15, hi = lane >> 4;

    f32x4 acc[16];
#pragma unroll
    for (int i = 0; i < 16; ++i) acc[i] = (f32x4)0.f;

#pragma unroll
    for (int k0 = 0; k0 < 64; k0 += 32) {
        short8 a = *(const short8*)&Al[w * 16 + lr][k0 + hi * 8];
#pragma unroll
        for (int nf = 0; nf < 16; ++nf) {
            short8 b = *(const short8*)&Wl[nf * 16 + lr][k0 + hi * 8];
            acc[nf] = __builtin_amdgcn_mfma_f32_16x16x32_bf16(a, b, acc[nf], 0, 0, 0);
        }
    }

    const int ebase = e0 + w * 16 + hi * 4;
    int d[4], s[4];
#pragma unroll
    for (int r = 0; r < 4; ++r) { d[r] = dstIdx[ebase + r]; s[r] = srcIdx[ebase + r]; }

#pragma unroll
    for (int nf = 0; nf < 8; ++nf) {
        const int col = nf * 16 + lr;
        const float bfv = bcat[col], bsv = bcat[128 + col];
#pragma unroll
        for (int r = 0; r < 4; ++r) {
            const unsigned short* pd = Pbf + (size_t)d[r] * 512;
            const unsigned short* ps_ = Pbf + (size_t)s[r] * 512;
            float pf = acc[nf][r]     + bfv + bf2f(pd[col])       + bf2f(ps_[128 + col]);
            float ps = acc[nf + 8][r] + bsv + bf2f(pd[256 + col]) + bf2f(ps_[384 + col]);
            float sig = 1.f / (1.f + __expf(-pf));
            float t = __expf(-fabsf(ps));
            float sp = fmaxf(ps, 0.f) + __logf(1.f + t);
            unsafeAtomicAdd(&agg[(size_t)d[r] * FD + col], sig * sp);
        }
    }
}

// -------- BatchNorm stats over N rows --------
__global__ __launch_bounds__(256) void bn_stats_kernel(
    const float* __restrict__ agg, float* __restrict__ stats)
{
    const int tid = threadIdx.x;
    const int f = tid & 127;
    float s = 0.f, sq = 0.f;
    for (int row = blockIdx.x * 2 + (tid >> 7); row < N_NODES; row += gridDim.x * 2) {
        float v = agg[(size_t)row * FD + f];
        s += v; sq += v * v;
    }
    unsafeAtomicAdd(&stats[f], s);
    unsafeAtomicAdd(&stats[128 + f], sq);
}

// -------- h = relu(h + BN(agg)); atomicMax into per-graph max --------
__global__ __launch_bounds__(256) void bn_update_kernel(
    float* __restrict__ h, const float* __restrict__ agg,
    const float* __restrict__ stats, const float* __restrict__ g,
    const float* __restrict__ b, const int* __restrict__ batch,
    float* __restrict__ gmax)
{
    const int tid = threadIdx.x;
    const int row = blockIdx.x * 2 + (tid >> 7);
    if (row >= N_NODES) return;
    const int f = tid & 127;
    const float inv = 1.f / (float)N_NODES;
    float mu = stats[f] * inv;
    float var = stats[128 + f] * inv - mu * mu;
    float rs = rsqrtf(var + 1e-5f);
    size_t idx = (size_t)row * FD + f;
    float v = h[idx] + (agg[idx] - mu) * rs * g[f] + b[f];
    v = fmaxf(v, 0.f);
    h[idx] = v;
    atomicMax((unsigned*)&gmax[batch[row] * FD + f], __float_as_uint(v));
}

__global__ __launch_bounds__(256) void gf_acc_kernel(float* __restrict__ gf, const float* __restrict__ gmax)
{
    int i = blockIdx.x * 256 + threadIdx.x;
    gf[i] += gmax[i];
}

// -------- head --------
__global__ __launch_bounds__(128) void head_y_kernel(
    const float* __restrict__ gf, const float* __restrict__ w1,
    const float* __restrict__ b1, float* __restrict__ y)
{
    __shared__ float row[128];
    int g = blockIdx.x, j = threadIdx.x;
    row[j] = gf[g * FD + j];
    __syncthreads();
    float acc = b1[j];
    for (int k = 0; k < FD; ++k) acc = fmaf(row[k], w1[k * FD + j], acc);
    y[g * FD + j] = acc;
}

__global__ __launch_bounds__(128) void head_stats_kernel(
    const float* __restrict__ y, float* __restrict__ hstat)
{
    int f = threadIdx.x;
    float s = 0.f, sq = 0.f;
    for (int g = 0; g < NG; ++g) { float v = y[g * FD + f]; s += v; sq += v * v; }
    float mu = s / (float)NG;
    float var = sq / (float)NG - mu * mu;
    hstat[f] = mu;
    hstat[128 + f] = rsqrtf(var + 1e-5f);
}

__global__ __launch_bounds__(128) void head_out_kernel(
    const float* __restrict__ y, const float* __restrict__ hstat,
    const float* __restrict__ bng, const float* __restrict__ bnb,
    const float* __restrict__ w2, const float* __restrict__ b2,
    float* __restrict__ out)
{
    __shared__ float part[2];
    int g = blockIdx.x, f = threadIdx.x;
    float v = (y[g * FD + f] - hstat[f]) * hstat[128 + f] * bng[f] + bnb[f];
    v = fmaxf(v, 0.f) * w2[f];
    for (int o = 32; o > 0; o >>= 1) v += __shfl_down(v, o);
    if ((f & 63) == 0) part[f >> 6] = v;
    __syncthreads();
    if (f == 0) out[g] = part[0] + part[1] + b2[0];
}

extern "C" void kernel_launch(void* const* d_in, const int* in_sizes, int n_in,
                              void* d_out, int out_size, void* d_ws, size_t ws_size,
                              hipStream_t stream)
{
    const float* x        = (const float*)d_in[0];
    const float* edge_attr= (const float*)d_in[1];
    const float* w_emb0   = (const float*)d_in[2];
    const float* w_emb1   = (const float*)d_in[3];
    const float* wf       = (const float*)d_in[4];
    const float* bf       = (const float*)d_in[5];
    const float* wsw      = (const float*)d_in[6];
    const float* bs       = (const float*)d_in[7];
    const float* bn_g     = (const float*)d_in[8];
    const float* bn_b     = (const float*)d_in[9];
    const float* w1       = (const float*)d_in[10];
    const float* b1       = (const float*)d_in[11];
    const float* bng      = (const float*)d_in[12];
    const float* bnb      = (const float*)d_in[13];
    const float* w2       = (const float*)d_in[14];
    const float* b2       = (const float*)d_in[15];
    const int*   eidx     = (const int*)d_in[16];   // [2][E]: row0=src, row1=dst
    const int*   batch    = (const int*)d_in[17];

    char* base = (char*)d_ws;
    size_t off = 0;
    auto alloc = [&](size_t bytes) -> void* {
        void* p = base + off;
        off += (bytes + 255) & ~(size_t)255;
        return p;
    };
    float*          h      = (float*)alloc((size_t)N_NODES * FD * 4);
    unsigned short* Pbf    = (unsigned short*)alloc((size_t)N_NODES * 512 * 2);
    float*          agg    = (float*)alloc((size_t)N_NODES * FD * 4);   // also embed tmp
    float*          Bcat   = (float*)alloc((size_t)NL * FD * 512 * 4);
    unsigned short* WecatT = (unsigned short*)alloc((size_t)NL * 256 * 64 * 2);
    float*          bcat   = (float*)alloc((size_t)NL * 256 * 4);
    unsigned short* eabf   = (unsigned short*)alloc((size_t)N_EDGES * 64 * 2);
    float*          stats  = (float*)alloc(256 * 4);
    float*          gmax   = (float*)alloc((size_t)NG * FD * 4);
    float*          gf     = (float*)alloc((size_t)NG * FD * 4);
    float*          y      = (float*)alloc((size_t)NG * FD * 4);
    float*          hstat  = (float*)alloc(256 * 4);

    const int MB = (N_NODES + 63) / 64;  // 782

    build_bcat_kernel<<<(NL * FD * 512 + 255) / 256, 256, 0, stream>>>(wf, wsw, Bcat);
    build_wecat_kernel<<<(NL * 256 * 64 + 255) / 256, 256, 0, stream>>>(wf, wsw, bf, bs, WecatT, bcat);
    ea2bf_kernel<<<(N_EDGES * 64) / 256, 256, 0, stream>>>(edge_attr, eabf);

    // embedding MLP: t0 = relu(x@w_emb0); h = t0@w_emb1   (t0 uses agg buffer)
    gemm_kernel<96, 1, 0><<<dim3(2, MB), 256, 0, stream>>>(x, w_emb0, agg, N_NODES, FIN, FD);
    gemm_kernel<128, 0, 0><<<dim3(2, MB), 256, 0, stream>>>(agg, w_emb1, h, N_NODES, FD, FD);

    hipMemsetAsync(gf, 0, (size_t)NG * FD * 4, stream);

    for (int l = 0; l < NL; ++l) {
        hipMemsetAsync(agg, 0, (size_t)N_NODES * FD * 4, stream);
        hipMemsetAsync(stats, 0, 256 * 4, stream);
        hipMemsetAsync(gmax, 0, (size_t)NG * FD * 4, stream);

        // P = h @ Bcat[l]  -> bf16 [N][512]
        gemm_kernel<128, 0, 1><<<dim3(8, MB), 256, 0, stream>>>(
            h, Bcat + (size_t)l * FD * 512, Pbf, N_NODES, FD, 512);

        msg3_kernel<<<N_EDGES / 64, 256, 0, stream>>>(
            Pbf, eabf, WecatT + (size_t)l * 256 * 64, bcat + (size_t)l * 256,
            eidx, eidx + N_EDGES, agg);

        bn_stats_kernel<<<512, 256, 0, stream>>>(agg, stats);
        bn_update_kernel<<<(N_NODES + 1) / 2, 256, 0, stream>>>(
            h, agg, stats, bn_g + l * FD, bn_b + l * FD, batch, gmax);
        gf_acc_kernel<<<(NG * FD) / 256, 256, 0, stream>>>(gf, gmax);
    }

    head_y_kernel<<<NG, 128, 0, stream>>>(gf, w1, b1, y);
    head_stats_kernel<<<1, 128, 0, stream>>>(y, hstat);
    head_out_kernel<<<NG, 128, 0, stream>>>(y, hstat, bng, bnb, w2, b2, (float*)d_out);
}

// Round 4
// 2431.160 us; speedup vs baseline: 2.5570x; 1.1250x over previous
//
#include <hip/hip_runtime.h>
#include <hip/hip_bf16.h>

#define N_NODES 50000
#define N_EDGES 800000
#define FIN 92
#define FD 128
#define DE 50
#define NL 3
#define NG 256

typedef short short8 __attribute__((ext_vector_type(8)));
typedef float f32x4 __attribute__((ext_vector_type(4)));

__device__ __forceinline__ short f2bf(float f) {
    unsigned u = __builtin_bit_cast(unsigned, f);
    unsigned r = (u + 0x7FFFu + ((u >> 16) & 1u)) >> 16;
    return (short)r;
}
__device__ __forceinline__ float bf2f(unsigned short b) {
    unsigned u = ((unsigned)b) << 16;
    return __builtin_bit_cast(float, u);
}

// ---------------- bf16-MFMA GEMM: C[M,Nc] = A[M,K] @ B[K,Nc] ----------------
// grid: (n-blocks, m-blocks) -- n fastest so blocks sharing an A-tile co-dispatch (L2 reuse)
template<int KPAD, int RELU, int OUTBF>
__global__ __launch_bounds__(256) void gemm_kernel(
    const float* __restrict__ A, const float* __restrict__ B,
    void* __restrict__ Cout, int M, int K, int Nc)
{
    __shared__ short Alds[64][KPAD + 8];
    __shared__ short Blds[64][KPAD + 8];   // holds B^T tile: [n][k]
    const int tid = threadIdx.x;
    const int m0 = blockIdx.y * 64;
    const int n0 = blockIdx.x * 64;

    for (int i = tid; i < 64 * KPAD; i += 256) {
        int r = i / KPAD, k = i - r * KPAD;
        int row = m0 + r;
        float v = (row < M && k < K) ? A[(size_t)row * K + k] : 0.f;
        Alds[r][k] = f2bf(v);
    }
    for (int i = tid; i < 64 * KPAD; i += 256) {
        int n = i & 63, k = i >> 6;
        float v = (k < K) ? B[(size_t)k * Nc + n0 + n] : 0.f;
        Blds[n][k] = f2bf(v);
    }
    __syncthreads();

    const int wv = tid >> 6, lane = tid & 63;
    const int lr = lane & 15, lk = (lane >> 4) * 8;
    f32x4 acc[4];
#pragma unroll
    for (int i = 0; i < 4; ++i) acc[i] = (f32x4)0.f;

    for (int k0 = 0; k0 < KPAD; k0 += 32) {
        short8 a = *(const short8*)&Alds[wv * 16 + lr][k0 + lk];
#pragma unroll
        for (int nf = 0; nf < 4; ++nf) {
            short8 b = *(const short8*)&Blds[nf * 16 + lr][k0 + lk];
            acc[nf] = __builtin_amdgcn_mfma_f32_16x16x32_bf16(a, b, acc[nf], 0, 0, 0);
        }
    }
#pragma unroll
    for (int nf = 0; nf < 4; ++nf) {
#pragma unroll
        for (int r = 0; r < 4; ++r) {
            int row = m0 + wv * 16 + (lane >> 4) * 4 + r;
            int col = n0 + nf * 16 + lr;
            if (row < M) {
                float v = acc[nf][r];
                if (RELU) v = fmaxf(v, 0.f);
                if (OUTBF) ((unsigned short*)Cout)[(size_t)row * Nc + col] = (unsigned short)f2bf(v);
                else       ((float*)Cout)[(size_t)row * Nc + col] = v;
            }
        }
    }
}

// -------- build concatenated per-layer node-projection weights: Bcat[l][128][512] --------
__global__ __launch_bounds__(256) void build_bcat_kernel(
    const float* __restrict__ wf, const float* __restrict__ wsw, float* __restrict__ Bcat)
{
    int i = blockIdx.x * 256 + threadIdx.x;
    if (i >= NL * FD * 512) return;
    int l = i / (FD * 512);
    int r = i - l * FD * 512;
    int k = r >> 9, j = r & 511;
    const float* Wm = (j < 256) ? wf : wsw;
    int jj = j & 255;
    int krow = (jj < FD) ? k : (FD + k);
    int col = jj & 127;
    Bcat[i] = Wm[((size_t)l * 306 + krow) * FD + col];
}

// -------- build transposed bf16 edge-proj weights WecatT[l][256][64] + bias bcat[l][256] ----
__global__ __launch_bounds__(256) void build_wecat_kernel(
    const float* __restrict__ wf, const float* __restrict__ wsw,
    const float* __restrict__ bf, const float* __restrict__ bs,
    unsigned short* __restrict__ WecatT, float* __restrict__ bcat)
{
    int i = blockIdx.x * 256 + threadIdx.x;
    if (i < NL * 256 * 64) {
        int l = i / (256 * 64);
        int r = i - l * 256 * 64;
        int col = r >> 6, k = r & 63;
        float v = 0.f;
        if (k < DE) {
            const float* W = (col < 128) ? wf : wsw;
            v = W[((size_t)l * 306 + 256 + k) * FD + (col & 127)];
        }
        WecatT[i] = (unsigned short)f2bf(v);
    }
    if (i < NL * 256) {
        int l = i >> 8, j = i & 255;
        bcat[i] = (j < 128) ? bf[l * FD + j] : bs[l * FD + (j & 127)];
    }
}

// ================= dst-sorted edge permutation (counting sort) =================
__global__ __launch_bounds__(256) void hist_kernel(
    const int* __restrict__ dstIdx, int* __restrict__ counts)
{
    int e = blockIdx.x * 256 + threadIdx.x;
    if (e < N_EDGES) atomicAdd(&counts[dstIdx[e]], 1);
}

__global__ __launch_bounds__(1024) void scan_kernel(
    const int* __restrict__ counts, int* __restrict__ cursor)
{
    __shared__ int part[1024];
    const int t = threadIdx.x;
    const int CH = 49;  // 1024*49 >= 50000
    const int base = t * CH;
    int s = 0;
    for (int i = 0; i < CH; ++i) {
        int idx = base + i;
        if (idx < N_NODES) s += counts[idx];
    }
    part[t] = s;
    __syncthreads();
    int v = s;
    for (int off = 1; off < 1024; off <<= 1) {
        int add = (t >= off) ? part[t - off] : 0;
        __syncthreads();
        v += add;
        part[t] = v;
        __syncthreads();
    }
    int pre = (t == 0) ? 0 : part[t - 1];
    for (int i = 0; i < CH; ++i) {
        int idx = base + i;
        if (idx < N_NODES) {
            cursor[idx] = pre;
            pre += counts[idx];
        }
    }
}

__global__ __launch_bounds__(256) void scatter_kernel(
    const int* __restrict__ eidx, int* __restrict__ cursor,
    int* __restrict__ perm, int* __restrict__ srcS, int* __restrict__ dstS)
{
    int e = blockIdx.x * 256 + threadIdx.x;
    if (e >= N_EDGES) return;
    int d = eidx[N_EDGES + e];
    int pos = atomicAdd(&cursor[d], 1);
    perm[pos] = e;
    srcS[pos] = eidx[e];
    dstS[pos] = d;
}

// -------- edge_attr -> bf16 padded [E][64], gathered into dst-sorted order --------
__global__ __launch_bounds__(256) void ea2bf_kernel(
    const float* __restrict__ ea, const int* __restrict__ perm,
    unsigned short* __restrict__ out)
{
    int i = blockIdx.x * 256 + threadIdx.x;
    if (i >= N_EDGES * 64) return;
    int e = i >> 6, k = i & 63;
    int pe = perm[e];
    out[i] = (k < DE) ? (unsigned short)f2bf(ea[(size_t)pe * DE + k]) : 0;
}

// ===== fused MFMA message kernel on dst-sorted edges (no LDS) =====
// Fragment layout: edge = e0 + w*16 + hi*4 + r, col = nf*16 + lr
//   filter pre-act = acc[nf][r], soft pre-act = acc[nf+8][r]  (same lane)
// dst runs are contiguous -> register-combine consecutive-r adds, atomics stay L2-local.
__global__ __launch_bounds__(256) void msg4_kernel(
    const unsigned short* __restrict__ Pbf,     // [N][512] bf16: dstF|srcF|dstS|srcS
    const unsigned short* __restrict__ eabf,    // [E][64] bf16, dst-sorted
    const unsigned short* __restrict__ WecatT,  // [256][64] bf16 (layer offset applied)
    const float* __restrict__ bcat,             // [256]  (layer offset applied)
    const int* __restrict__ srcS, const int* __restrict__ dstS,
    float* __restrict__ agg)
{
    const int tid = threadIdx.x;
    const int e0 = blockIdx.x * 64;
    const int w = tid >> 6, lane = tid & 63;
    const int lr = lane & 15, hi = lane >> 4;

    f32x4 acc[16];
#pragma unroll
    for (int i = 0; i < 16; ++i) acc[i] = (f32x4)0.f;

    const size_t arow = (size_t)(e0 + w * 16 + lr) * 64;
#pragma unroll
    for (int k0 = 0; k0 < 64; k0 += 32) {
        short8 a = *(const short8*)&eabf[arow + k0 + hi * 8];
#pragma unroll
        for (int nf = 0; nf < 16; ++nf) {
            short8 b = *(const short8*)&WecatT[(size_t)(nf * 16 + lr) * 64 + k0 + hi * 8];
            acc[nf] = __builtin_amdgcn_mfma_f32_16x16x32_bf16(a, b, acc[nf], 0, 0, 0);
        }
    }

    const int ebase = e0 + w * 16 + hi * 4;
    int d[4], s[4];
#pragma unroll
    for (int r = 0; r < 4; ++r) { d[r] = dstS[ebase + r]; s[r] = srcS[ebase + r]; }
    const bool eq01 = (d[0] == d[1]), eq12 = (d[1] == d[2]), eq23 = (d[2] == d[3]);

#pragma unroll
    for (int nf = 0; nf < 8; ++nf) {
        const int col = nf * 16 + lr;
        const float bfv = bcat[col], bsv = bcat[128 + col];
        float m[4];
#pragma unroll
        for (int r = 0; r < 4; ++r) {
            const unsigned short* pd  = Pbf + (size_t)d[r] * 512;
            const unsigned short* ps_ = Pbf + (size_t)s[r] * 512;
            float pf = acc[nf][r]     + bfv + bf2f(pd[col])       + bf2f(ps_[128 + col]);
            float ps = acc[nf + 8][r] + bsv + bf2f(pd[256 + col]) + bf2f(ps_[384 + col]);
            float sig = 1.f / (1.f + __expf(-pf));
            float t = __expf(-fabsf(ps));
            float sp = fmaxf(ps, 0.f) + __logf(1.f + t);
            m[r] = sig * sp;
        }
        float a0 = m[0];
        if (eq01) a0 += m[1];
        else { unsafeAtomicAdd(&agg[(size_t)d[0] * FD + col], a0); a0 = m[1]; }
        if (eq12) a0 += m[2];
        else { unsafeAtomicAdd(&agg[(size_t)d[1] * FD + col], a0); a0 = m[2]; }
        if (eq23) a0 += m[3];
        else { unsafeAtomicAdd(&agg[(size_t)d[2] * FD + col], a0); a0 = m[3]; }
        unsafeAtomicAdd(&agg[(size_t)d[3] * FD + col], a0);
    }
}

// -------- BatchNorm stats over N rows --------
__global__ __launch_bounds__(256) void bn_stats_kernel(
    const float* __restrict__ agg, float* __restrict__ stats)
{
    const int tid = threadIdx.x;
    const int f = tid & 127;
    float s = 0.f, sq = 0.f;
    for (int row = blockIdx.x * 2 + (tid >> 7); row < N_NODES; row += gridDim.x * 2) {
        float v = agg[(size_t)row * FD + f];
        s += v; sq += v * v;
    }
    unsafeAtomicAdd(&stats[f], s);
    unsafeAtomicAdd(&stats[128 + f], sq);
}

// -------- h = relu(h + BN(agg)); atomicMax into per-graph max --------
__global__ __launch_bounds__(256) void bn_update_kernel(
    float* __restrict__ h, const float* __restrict__ agg,
    const float* __restrict__ stats, const float* __restrict__ g,
    const float* __restrict__ b, const int* __restrict__ batch,
    float* __restrict__ gmax)
{
    const int tid = threadIdx.x;
    const int row = blockIdx.x * 2 + (tid >> 7);
    if (row >= N_NODES) return;
    const int f = tid & 127;
    const float inv = 1.f / (float)N_NODES;
    float mu = stats[f] * inv;
    float var = stats[128 + f] * inv - mu * mu;
    float rs = rsqrtf(var + 1e-5f);
    size_t idx = (size_t)row * FD + f;
    float v = h[idx] + (agg[idx] - mu) * rs * g[f] + b[f];
    v = fmaxf(v, 0.f);
    h[idx] = v;
    atomicMax((unsigned*)&gmax[batch[row] * FD + f], __float_as_uint(v));
}

__global__ __launch_bounds__(256) void gf_acc_kernel(float* __restrict__ gf, const float* __restrict__ gmax)
{
    int i = blockIdx.x * 256 + threadIdx.x;
    gf[i] += gmax[i];
}

// -------- head --------
__global__ __launch_bounds__(128) void head_y_kernel(
    const float* __restrict__ gf, const float* __restrict__ w1,
    const float* __restrict__ b1, float* __restrict__ y)
{
    __shared__ float row[128];
    int g = blockIdx.x, j = threadIdx.x;
    row[j] = gf[g * FD + j];
    __syncthreads();
    float acc = b1[j];
    for (int k = 0; k < FD; ++k) acc = fmaf(row[k], w1[k * FD + j], acc);
    y[g * FD + j] = acc;
}

__global__ __launch_bounds__(128) void head_stats_kernel(
    const float* __restrict__ y, float* __restrict__ hstat)
{
    int f = threadIdx.x;
    float s = 0.f, sq = 0.f;
    for (int g = 0; g < NG; ++g) { float v = y[g * FD + f]; s += v; sq += v * v; }
    float mu = s / (float)NG;
    float var = sq / (float)NG - mu * mu;
    hstat[f] = mu;
    hstat[128 + f] = rsqrtf(var + 1e-5f);
}

__global__ __launch_bounds__(128) void head_out_kernel(
    const float* __restrict__ y, const float* __restrict__ hstat,
    const float* __restrict__ bng, const float* __restrict__ bnb,
    const float* __restrict__ w2, const float* __restrict__ b2,
    float* __restrict__ out)
{
    __shared__ float part[2];
    int g = blockIdx.x, f = threadIdx.x;
    float v = (y[g * FD + f] - hstat[f]) * hstat[128 + f] * bng[f] + bnb[f];
    v = fmaxf(v, 0.f) * w2[f];
    for (int o = 32; o > 0; o >>= 1) v += __shfl_down(v, o);
    if ((f & 63) == 0) part[f >> 6] = v;
    __syncthreads();
    if (f == 0) out[g] = part[0] + part[1] + b2[0];
}

extern "C" void kernel_launch(void* const* d_in, const int* in_sizes, int n_in,
                              void* d_out, int out_size, void* d_ws, size_t ws_size,
                              hipStream_t stream)
{
    const float* x        = (const float*)d_in[0];
    const float* edge_attr= (const float*)d_in[1];
    const float* w_emb0   = (const float*)d_in[2];
    const float* w_emb1   = (const float*)d_in[3];
    const float* wf       = (const float*)d_in[4];
    const float* bf       = (const float*)d_in[5];
    const float* wsw      = (const float*)d_in[6];
    const float* bs       = (const float*)d_in[7];
    const float* bn_g     = (const float*)d_in[8];
    const float* bn_b     = (const float*)d_in[9];
    const float* w1       = (const float*)d_in[10];
    const float* b1       = (const float*)d_in[11];
    const float* bng      = (const float*)d_in[12];
    const float* bnb      = (const float*)d_in[13];
    const float* w2       = (const float*)d_in[14];
    const float* b2       = (const float*)d_in[15];
    const int*   eidx     = (const int*)d_in[16];   // [2][E]: row0=src, row1=dst
    const int*   batch    = (const int*)d_in[17];

    char* base = (char*)d_ws;
    size_t off = 0;
    auto alloc = [&](size_t bytes) -> void* {
        void* p = base + off;
        off += (bytes + 255) & ~(size_t)255;
        return p;
    };
    float*          h      = (float*)alloc((size_t)N_NODES * FD * 4);
    unsigned short* Pbf    = (unsigned short*)alloc((size_t)N_NODES * 512 * 2);
    float*          agg    = (float*)alloc((size_t)N_NODES * FD * 4);   // also embed tmp + sort scratch
    float*          Bcat   = (float*)alloc((size_t)NL * FD * 512 * 4);
    unsigned short* WecatT = (unsigned short*)alloc((size_t)NL * 256 * 64 * 2);
    float*          bcat   = (float*)alloc((size_t)NL * 256 * 4);
    unsigned short* eabf   = (unsigned short*)alloc((size_t)N_EDGES * 64 * 2);
    int*            srcS   = (int*)alloc((size_t)N_EDGES * 4);
    int*            dstS   = (int*)alloc((size_t)N_EDGES * 4);
    float*          stats  = (float*)alloc(256 * 4);
    float*          gmax   = (float*)alloc((size_t)NG * FD * 4);
    float*          gf     = (float*)alloc((size_t)NG * FD * 4);
    float*          y      = (float*)alloc((size_t)NG * FD * 4);
    float*          hstat  = (float*)alloc(256 * 4);

    // sort scratch overlaid on agg (dead until layer loop; all sort users complete first)
    int* perm   = (int*)agg;               // [E]
    int* counts = perm + N_EDGES;          // [N]
    int* cursor = counts + N_NODES;        // [N]

    const int MB = (N_NODES + 63) / 64;  // 782

    // ---- dst-sort the edges (once, reused across layers) ----
    hipMemsetAsync(counts, 0, (size_t)N_NODES * 4, stream);
    hist_kernel<<<(N_EDGES + 255) / 256, 256, 0, stream>>>(eidx + N_EDGES, counts);
    scan_kernel<<<1, 1024, 0, stream>>>(counts, cursor);
    scatter_kernel<<<(N_EDGES + 255) / 256, 256, 0, stream>>>(eidx, cursor, perm, srcS, dstS);
    ea2bf_kernel<<<(N_EDGES * 64) / 256, 256, 0, stream>>>(edge_attr, perm, eabf);

    build_bcat_kernel<<<(NL * FD * 512 + 255) / 256, 256, 0, stream>>>(wf, wsw, Bcat);
    build_wecat_kernel<<<(NL * 256 * 64 + 255) / 256, 256, 0, stream>>>(wf, wsw, bf, bs, WecatT, bcat);

    // embedding MLP: t0 = relu(x@w_emb0); h = t0@w_emb1   (t0 uses agg buffer, after sort done)
    gemm_kernel<96, 1, 0><<<dim3(2, MB), 256, 0, stream>>>(x, w_emb0, agg, N_NODES, FIN, FD);
    gemm_kernel<128, 0, 0><<<dim3(2, MB), 256, 0, stream>>>(agg, w_emb1, h, N_NODES, FD, FD);

    hipMemsetAsync(gf, 0, (size_t)NG * FD * 4, stream);

    for (int l = 0; l < NL; ++l) {
        hipMemsetAsync(agg, 0, (size_t)N_NODES * FD * 4, stream);
        hipMemsetAsync(stats, 0, 256 * 4, stream);
        hipMemsetAsync(gmax, 0, (size_t)NG * FD * 4, stream);

        // P = h @ Bcat[l]  -> bf16 [N][512]
        gemm_kernel<128, 0, 1><<<dim3(8, MB), 256, 0, stream>>>(
            h, Bcat + (size_t)l * FD * 512, Pbf, N_NODES, FD, 512);

        msg4_kernel<<<N_EDGES / 64, 256, 0, stream>>>(
            Pbf, eabf, WecatT + (size_t)l * 256 * 64, bcat + (size_t)l * 256,
            srcS, dstS, agg);

        bn_stats_kernel<<<512, 256, 0, stream>>>(agg, stats);
        bn_update_kernel<<<(N_NODES + 1) / 2, 256, 0, stream>>>(
            h, agg, stats, bn_g + l * FD, bn_b + l * FD, batch, gmax);
        gf_acc_kernel<<<(NG * FD) / 256, 256, 0, stream>>>(gf, gmax);
    }

    head_y_kernel<<<NG, 128, 0, stream>>>(gf, w1, b1, y);
    head_stats_kernel<<<1, 128, 0, stream>>>(y, hstat);
    head_out_kernel<<<NG, 128, 0, stream>>>(y, hstat, bng, bnb, w2, b2, (float*)d_out);
}

// Round 5
// 2259.369 us; speedup vs baseline: 2.7514x; 1.0760x over previous
//
#include <hip/hip_runtime.h>
#include <hip/hip_bf16.h>

#define N_NODES 50000
#define N_EDGES 800000
#define FIN 92
#define FD 128
#define DE 50
#define NL 3
#define NG 256
#define MPAD 130

typedef short short8 __attribute__((ext_vector_type(8)));
typedef float f32x4 __attribute__((ext_vector_type(4)));

__device__ __forceinline__ short f2bf(float f) {
    unsigned u = __builtin_bit_cast(unsigned, f);
    unsigned r = (u + 0x7FFFu + ((u >> 16) & 1u)) >> 16;
    return (short)r;
}
__device__ __forceinline__ float bf2f(unsigned short b) {
    unsigned u = ((unsigned)b) << 16;
    return __builtin_bit_cast(float, u);
}

// ---------------- fp32-input bf16-MFMA GEMM (embedding only) ----------------
template<int KPAD, int RELU, int OUTBF>
__global__ __launch_bounds__(256) void gemm_kernel(
    const float* __restrict__ A, const float* __restrict__ B,
    void* __restrict__ Cout, int M, int K, int Nc)
{
    __shared__ short Alds[64][KPAD + 8];
    __shared__ short Blds[64][KPAD + 8];   // holds B^T tile: [n][k]
    const int tid = threadIdx.x;
    const int m0 = blockIdx.y * 64;
    const int n0 = blockIdx.x * 64;

    for (int i = tid; i < 64 * KPAD; i += 256) {
        int r = i / KPAD, k = i - r * KPAD;
        int row = m0 + r;
        float v = (row < M && k < K) ? A[(size_t)row * K + k] : 0.f;
        Alds[r][k] = f2bf(v);
    }
    for (int i = tid; i < 64 * KPAD; i += 256) {
        int n = i & 63, k = i >> 6;
        float v = (k < K) ? B[(size_t)k * Nc + n0 + n] : 0.f;
        Blds[n][k] = f2bf(v);
    }
    __syncthreads();

    const int wv = tid >> 6, lane = tid & 63;
    const int lr = lane & 15, lk = (lane >> 4) * 8;
    f32x4 acc[4];
#pragma unroll
    for (int i = 0; i < 4; ++i) acc[i] = (f32x4)0.f;

    for (int k0 = 0; k0 < KPAD; k0 += 32) {
        short8 a = *(const short8*)&Alds[wv * 16 + lr][k0 + lk];
#pragma unroll
        for (int nf = 0; nf < 4; ++nf) {
            short8 b = *(const short8*)&Blds[nf * 16 + lr][k0 + lk];
            acc[nf] = __builtin_amdgcn_mfma_f32_16x16x32_bf16(a, b, acc[nf], 0, 0, 0);
        }
    }
#pragma unroll
    for (int nf = 0; nf < 4; ++nf) {
#pragma unroll
        for (int r = 0; r < 4; ++r) {
            int row = m0 + wv * 16 + (lane >> 4) * 4 + r;
            int col = n0 + nf * 16 + lr;
            if (row < M) {
                float v = acc[nf][r];
                if (RELU) v = fmaxf(v, 0.f);
                if (OUTBF) ((unsigned short*)Cout)[(size_t)row * Nc + col] = (unsigned short)f2bf(v);
                else       ((float*)Cout)[(size_t)row * Nc + col] = v;
            }
        }
    }
}

// ---------------- all-bf16 GEMM for P: A[M][128] bf16, Bt[Nc][128] bf16 ----------------
__global__ __launch_bounds__(256) void gemm_bb_kernel(
    const unsigned short* __restrict__ Abf, const unsigned short* __restrict__ Bt,
    unsigned short* __restrict__ Cout, int M, int Nc)
{
    __shared__ short Alds[64][136];
    __shared__ short Blds[64][136];
    const int tid = threadIdx.x;
    const int m0 = blockIdx.y * 64;
    const int n0 = blockIdx.x * 64;

    for (int i = tid; i < 1024; i += 256) {   // 64 rows x 16 segs of 8 shorts
        int r = i >> 4, seg = i & 15;
        int row = m0 + r;
        short8 va = (row < M) ? *(const short8*)&Abf[(size_t)row * 128 + seg * 8] : (short8)0;
        *(short8*)&Alds[r][seg * 8] = va;
        *(short8*)&Blds[r][seg * 8] = *(const short8*)&Bt[(size_t)(n0 + r) * 128 + seg * 8];
    }
    __syncthreads();

    const int wv = tid >> 6, lane = tid & 63;
    const int lr = lane & 15, lk = (lane >> 4) * 8;
    f32x4 acc[4];
#pragma unroll
    for (int i = 0; i < 4; ++i) acc[i] = (f32x4)0.f;

#pragma unroll
    for (int k0 = 0; k0 < 128; k0 += 32) {
        short8 a = *(const short8*)&Alds[wv * 16 + lr][k0 + lk];
#pragma unroll
        for (int nf = 0; nf < 4; ++nf) {
            short8 b = *(const short8*)&Blds[nf * 16 + lr][k0 + lk];
            acc[nf] = __builtin_amdgcn_mfma_f32_16x16x32_bf16(a, b, acc[nf], 0, 0, 0);
        }
    }
#pragma unroll
    for (int nf = 0; nf < 4; ++nf) {
#pragma unroll
        for (int r = 0; r < 4; ++r) {
            int row = m0 + wv * 16 + (lane >> 4) * 4 + r;
            int col = n0 + nf * 16 + lr;
            if (row < M)
                Cout[(size_t)row * Nc + col] = (unsigned short)f2bf(acc[nf][r]);
        }
    }
}

// -------- build transposed bf16 node-projection weights: BcatT[l][512][128] ([n][k]) -----
__global__ __launch_bounds__(256) void build_bcatT_kernel(
    const float* __restrict__ wf, const float* __restrict__ wsw, unsigned short* __restrict__ BcatT)
{
    int i = blockIdx.x * 256 + threadIdx.x;
    if (i >= NL * 512 * 128) return;
    int l = i / (512 * 128);
    int r = i - l * 512 * 128;
    int n = r >> 7, k = r & 127;
    const float* Wm = (n < 256) ? wf : wsw;
    int jj = n & 255;
    int krow = (jj < 128) ? k : (128 + k);
    int col = jj & 127;
    BcatT[i] = (unsigned short)f2bf(Wm[((size_t)l * 306 + krow) * FD + col]);
}

// -------- build transposed bf16 edge-proj weights WecatT[l][256][64] + bias bcat[l][256] ----
__global__ __launch_bounds__(256) void build_wecat_kernel(
    const float* __restrict__ wf, const float* __restrict__ wsw,
    const float* __restrict__ bf, const float* __restrict__ bs,
    unsigned short* __restrict__ WecatT, float* __restrict__ bcat)
{
    int i = blockIdx.x * 256 + threadIdx.x;
    if (i < NL * 256 * 64) {
        int l = i / (256 * 64);
        int r = i - l * 256 * 64;
        int col = r >> 6, k = r & 63;
        float v = 0.f;
        if (k < DE) {
            const float* W = (col < 128) ? wf : wsw;
            v = W[((size_t)l * 306 + 256 + k) * FD + (col & 127)];
        }
        WecatT[i] = (unsigned short)f2bf(v);
    }
    if (i < NL * 256) {
        int l = i >> 8, j = i & 255;
        bcat[i] = (j < 128) ? bf[l * FD + j] : bs[l * FD + (j & 127)];
    }
}

// -------- h fp32 -> bf16 mirror --------
__global__ __launch_bounds__(256) void h2bf_kernel(
    const float* __restrict__ h, unsigned short* __restrict__ hbf)
{
    int i = blockIdx.x * 256 + threadIdx.x;
    if (i >= N_NODES * FD / 4) return;
    f32x4 v = *(const f32x4*)&h[i * 4];
    unsigned short o[4];
#pragma unroll
    for (int j = 0; j < 4; ++j) o[j] = (unsigned short)f2bf(v[j]);
    *(unsigned long long*)&hbf[i * 4] = *(unsigned long long*)o;
}

// ================= dst-sorted edge permutation (counting sort) =================
__global__ __launch_bounds__(256) void hist_kernel(
    const int* __restrict__ dstIdx, int* __restrict__ counts)
{
    int e = blockIdx.x * 256 + threadIdx.x;
    if (e < N_EDGES) atomicAdd(&counts[dstIdx[e]], 1);
}

__global__ __launch_bounds__(1024) void scan_kernel(
    const int* __restrict__ counts, int* __restrict__ cursor)
{
    __shared__ int part[1024];
    const int t = threadIdx.x;
    const int CH = 49;  // 1024*49 >= 50000
    const int base = t * CH;
    int s = 0;
    for (int i = 0; i < CH; ++i) {
        int idx = base + i;
        if (idx < N_NODES) s += counts[idx];
    }
    part[t] = s;
    __syncthreads();
    int v = s;
    for (int off = 1; off < 1024; off <<= 1) {
        int add = (t >= off) ? part[t - off] : 0;
        __syncthreads();
        v += add;
        part[t] = v;
        __syncthreads();
    }
    int pre = (t == 0) ? 0 : part[t - 1];
    for (int i = 0; i < CH; ++i) {
        int idx = base + i;
        if (idx < N_NODES) {
            cursor[idx] = pre;
            pre += counts[idx];
        }
    }
}

__global__ __launch_bounds__(256) void scatter_kernel(
    const int* __restrict__ eidx, int* __restrict__ cursor,
    int* __restrict__ perm, int* __restrict__ srcS, int* __restrict__ dstS)
{
    int e = blockIdx.x * 256 + threadIdx.x;
    if (e >= N_EDGES) return;
    int d = eidx[N_EDGES + e];
    int pos = atomicAdd(&cursor[d], 1);
    perm[pos] = e;
    srcS[pos] = eidx[e];
    dstS[pos] = d;
}

// -------- edge_attr -> bf16 padded [E][64], gathered into dst-sorted order --------
__global__ __launch_bounds__(256) void ea2bf_kernel(
    const float* __restrict__ ea, const int* __restrict__ perm,
    unsigned short* __restrict__ out)
{
    int i = blockIdx.x * 256 + threadIdx.x;
    if (i >= N_EDGES * 64) return;
    int e = i >> 6, k = i & 63;
    int pe = perm[e];
    out[i] = (k < DE) ? (unsigned short)f2bf(ea[(size_t)pe * DE + k]) : 0;
}

// ===== fused MFMA message kernel + LDS segment-sum over dst-sorted window =====
// Phase 1: MFMA edge-proj, gather P, gate -> mlds[64][128] (padded 130, 2-way free)
// Phase 2: 128 threads, one col each, walk the 64-edge window's dst runs:
//   interior runs (fully contained) -> plain store (block exclusively owns that dst);
//   boundary runs -> atomicAdd.
__global__ __launch_bounds__(256) void msg5_kernel(
    const unsigned short* __restrict__ Pbf,     // [N][512] bf16: dstF|srcF|dstS|srcS
    const unsigned short* __restrict__ eabf,    // [E][64] bf16, dst-sorted
    const unsigned short* __restrict__ WecatT,  // [256][64] bf16 (layer offset applied)
    const float* __restrict__ bcat,             // [256]  (layer offset applied)
    const int* __restrict__ srcS, const int* __restrict__ dstS,
    float* __restrict__ agg)
{
    __shared__ float mlds[64][MPAD];
    __shared__ int dlds[66];
    const int tid = threadIdx.x;
    const int e0 = blockIdx.x * 64;

    if (tid < 66) {
        int ge = e0 - 1 + tid;
        int v;
        if (ge < 0) v = -1;
        else if (ge >= N_EDGES) v = -2;
        else v = dstS[ge];
        dlds[tid] = v;
    }

    const int w = tid >> 6, lane = tid & 63;
    const int lr = lane & 15, hi = lane >> 4;

    f32x4 acc[16];
#pragma unroll
    for (int i = 0; i < 16; ++i) acc[i] = (f32x4)0.f;

    const size_t arow = (size_t)(e0 + w * 16 + lr) * 64;
#pragma unroll
    for (int k0 = 0; k0 < 64; k0 += 32) {
        short8 a = *(const short8*)&eabf[arow + k0 + hi * 8];
#pragma unroll
        for (int nf = 0; nf < 16; ++nf) {
            short8 b = *(const short8*)&WecatT[(size_t)(nf * 16 + lr) * 64 + k0 + hi * 8];
            acc[nf] = __builtin_amdgcn_mfma_f32_16x16x32_bf16(a, b, acc[nf], 0, 0, 0);
        }
    }

    const int ebase = e0 + w * 16 + hi * 4;
    const int eloc = w * 16 + hi * 4;
    int d[4], s[4];
#pragma unroll
    for (int r = 0; r < 4; ++r) { d[r] = dstS[ebase + r]; s[r] = srcS[ebase + r]; }

#pragma unroll
    for (int nf = 0; nf < 8; ++nf) {
        const int col = nf * 16 + lr;
        const float bfv = bcat[col], bsv = bcat[128 + col];
#pragma unroll
        for (int r = 0; r < 4; ++r) {
            const unsigned short* pd  = Pbf + (size_t)d[r] * 512;
            const unsigned short* ps_ = Pbf + (size_t)s[r] * 512;
            float pf = acc[nf][r]     + bfv + bf2f(pd[col])       + bf2f(ps_[128 + col]);
            float ps = acc[nf + 8][r] + bsv + bf2f(pd[256 + col]) + bf2f(ps_[384 + col]);
            float sig = 1.f / (1.f + __expf(-pf));
            float t = __expf(-fabsf(ps));
            float sp = fmaxf(ps, 0.f) + __logf(1.f + t);
            mlds[eloc + r][col] = sig * sp;
        }
    }
    __syncthreads();

    if (tid < 128) {
        const int c = tid;
        bool startsInside = (dlds[1] != dlds[0]);
        float run = 0.f;
        for (int e = 0; e < 64; ++e) {
            run += mlds[e][c];
            int de = dlds[e + 1];
            int dnext = dlds[e + 2];
            if (de != dnext) {   // run ends at this edge (uniform branch)
                if (startsInside) agg[(size_t)de * FD + c] = run;
                else unsafeAtomicAdd(&agg[(size_t)de * FD + c], run);
                run = 0.f;
                startsInside = true;
            }
        }
        if (run != 0.f)   // tail run continues into next window
            unsafeAtomicAdd(&agg[(size_t)dlds[64] * FD + c], run);
    }
}

// -------- BatchNorm stats over N rows --------
__global__ __launch_bounds__(256) void bn_stats_kernel(
    const float* __restrict__ agg, float* __restrict__ stats)
{
    const int tid = threadIdx.x;
    const int f = tid & 127;
    float s = 0.f, sq = 0.f;
    for (int row = blockIdx.x * 2 + (tid >> 7); row < N_NODES; row += gridDim.x * 2) {
        float v = agg[(size_t)row * FD + f];
        s += v; sq += v * v;
    }
    unsafeAtomicAdd(&stats[f], s);
    unsafeAtomicAdd(&stats[128 + f], sq);
}

// -------- h = relu(h + BN(agg)); write fp32 + bf16; atomicMax per-graph --------
__global__ __launch_bounds__(256) void bn_update_kernel(
    float* __restrict__ h, unsigned short* __restrict__ hbf,
    const float* __restrict__ agg,
    const float* __restrict__ stats, const float* __restrict__ g,
    const float* __restrict__ b, const int* __restrict__ batch,
    float* __restrict__ gmax)
{
    const int tid = threadIdx.x;
    const int row = blockIdx.x * 2 + (tid >> 7);
    if (row >= N_NODES) return;
    const int f = tid & 127;
    const float inv = 1.f / (float)N_NODES;
    float mu = stats[f] * inv;
    float var = stats[128 + f] * inv - mu * mu;
    float rs = rsqrtf(var + 1e-5f);
    size_t idx = (size_t)row * FD + f;
    float v = h[idx] + (agg[idx] - mu) * rs * g[f] + b[f];
    v = fmaxf(v, 0.f);
    h[idx] = v;
    hbf[idx] = (unsigned short)f2bf(v);
    atomicMax((unsigned*)&gmax[batch[row] * FD + f], __float_as_uint(v));
}

__global__ __launch_bounds__(256) void gf_acc_kernel(float* __restrict__ gf, const float* __restrict__ gmax)
{
    int i = blockIdx.x * 256 + threadIdx.x;
    gf[i] += gmax[i];
}

// -------- head --------
__global__ __launch_bounds__(128) void head_y_kernel(
    const float* __restrict__ gf, const float* __restrict__ w1,
    const float* __restrict__ b1, float* __restrict__ y)
{
    __shared__ float row[128];
    int g = blockIdx.x, j = threadIdx.x;
    row[j] = gf[g * FD + j];
    __syncthreads();
    float acc = b1[j];
    for (int k = 0; k < FD; ++k) acc = fmaf(row[k], w1[k * FD + j], acc);
    y[g * FD + j] = acc;
}

__global__ __launch_bounds__(128) void head_stats_kernel(
    const float* __restrict__ y, float* __restrict__ hstat)
{
    int f = threadIdx.x;
    float s = 0.f, sq = 0.f;
    for (int g = 0; g < NG; ++g) { float v = y[g * FD + f]; s += v; sq += v * v; }
    float mu = s / (float)NG;
    float var = sq / (float)NG - mu * mu;
    hstat[f] = mu;
    hstat[128 + f] = rsqrtf(var + 1e-5f);
}

__global__ __launch_bounds__(128) void head_out_kernel(
    const float* __restrict__ y, const float* __restrict__ hstat,
    const float* __restrict__ bng, const float* __restrict__ bnb,
    const float* __restrict__ w2, const float* __restrict__ b2,
    float* __restrict__ out)
{
    __shared__ float part[2];
    int g = blockIdx.x, f = threadIdx.x;
    float v = (y[g * FD + f] - hstat[f]) * hstat[128 + f] * bng[f] + bnb[f];
    v = fmaxf(v, 0.f) * w2[f];
    for (int o = 32; o > 0; o >>= 1) v += __shfl_down(v, o);
    if ((f & 63) == 0) part[f >> 6] = v;
    __syncthreads();
    if (f == 0) out[g] = part[0] + part[1] + b2[0];
}

extern "C" void kernel_launch(void* const* d_in, const int* in_sizes, int n_in,
                              void* d_out, int out_size, void* d_ws, size_t ws_size,
                              hipStream_t stream)
{
    const float* x        = (const float*)d_in[0];
    const float* edge_attr= (const float*)d_in[1];
    const float* w_emb0   = (const float*)d_in[2];
    const float* w_emb1   = (const float*)d_in[3];
    const float* wf       = (const float*)d_in[4];
    const float* bf       = (const float*)d_in[5];
    const float* wsw      = (const float*)d_in[6];
    const float* bs       = (const float*)d_in[7];
    const float* bn_g     = (const float*)d_in[8];
    const float* bn_b     = (const float*)d_in[9];
    const float* w1       = (const float*)d_in[10];
    const float* b1       = (const float*)d_in[11];
    const float* bng      = (const float*)d_in[12];
    const float* bnb      = (const float*)d_in[13];
    const float* w2       = (const float*)d_in[14];
    const float* b2       = (const float*)d_in[15];
    const int*   eidx     = (const int*)d_in[16];   // [2][E]: row0=src, row1=dst
    const int*   batch    = (const int*)d_in[17];

    char* base = (char*)d_ws;
    size_t off = 0;
    auto alloc = [&](size_t bytes) -> void* {
        void* p = base + off;
        off += (bytes + 255) & ~(size_t)255;
        return p;
    };
    float*          h      = (float*)alloc((size_t)N_NODES * FD * 4);
    unsigned short* hbf    = (unsigned short*)alloc((size_t)N_NODES * FD * 2);
    unsigned short* Pbf    = (unsigned short*)alloc((size_t)N_NODES * 512 * 2);
    float*          agg    = (float*)alloc((size_t)N_NODES * FD * 4);   // also embed tmp + sort scratch
    unsigned short* BcatT  = (unsigned short*)alloc((size_t)NL * 512 * 128 * 2);
    unsigned short* WecatT = (unsigned short*)alloc((size_t)NL * 256 * 64 * 2);
    float*          bcat   = (float*)alloc((size_t)NL * 256 * 4);
    unsigned short* eabf   = (unsigned short*)alloc((size_t)N_EDGES * 64 * 2);
    int*            srcS   = (int*)alloc((size_t)N_EDGES * 4);
    int*            dstS   = (int*)alloc((size_t)N_EDGES * 4);
    float*          stats  = (float*)alloc(256 * 4);
    float*          gmax   = (float*)alloc((size_t)NG * FD * 4);
    float*          gf     = (float*)alloc((size_t)NG * FD * 4);
    float*          y      = (float*)alloc((size_t)NG * FD * 4);
    float*          hstat  = (float*)alloc(256 * 4);

    // sort scratch overlaid on agg (dead until layer loop; all sort users complete first)
    int* perm   = (int*)agg;               // [E]
    int* counts = perm + N_EDGES;          // [N]
    int* cursor = counts + N_NODES;        // [N]

    const int MB = (N_NODES + 63) / 64;  // 782

    // ---- dst-sort the edges (once, reused across layers) ----
    hipMemsetAsync(counts, 0, (size_t)N_NODES * 4, stream);
    hist_kernel<<<(N_EDGES + 255) / 256, 256, 0, stream>>>(eidx + N_EDGES, counts);
    scan_kernel<<<1, 1024, 0, stream>>>(counts, cursor);
    scatter_kernel<<<(N_EDGES + 255) / 256, 256, 0, stream>>>(eidx, cursor, perm, srcS, dstS);
    ea2bf_kernel<<<(N_EDGES * 64) / 256, 256, 0, stream>>>(edge_attr, perm, eabf);

    build_bcatT_kernel<<<(NL * 512 * 128 + 255) / 256, 256, 0, stream>>>(wf, wsw, BcatT);
    build_wecat_kernel<<<(NL * 256 * 64 + 255) / 256, 256, 0, stream>>>(wf, wsw, bf, bs, WecatT, bcat);

    // embedding MLP: t0 = relu(x@w_emb0); h = t0@w_emb1   (t0 uses agg buffer, after sort done)
    gemm_kernel<96, 1, 0><<<dim3(2, MB), 256, 0, stream>>>(x, w_emb0, agg, N_NODES, FIN, FD);
    gemm_kernel<128, 0, 0><<<dim3(2, MB), 256, 0, stream>>>(agg, w_emb1, h, N_NODES, FD, FD);
    h2bf_kernel<<<(N_NODES * FD / 4 + 255) / 256, 256, 0, stream>>>(h, hbf);

    hipMemsetAsync(gf, 0, (size_t)NG * FD * 4, stream);

    for (int l = 0; l < NL; ++l) {
        hipMemsetAsync(agg, 0, (size_t)N_NODES * FD * 4, stream);
        hipMemsetAsync(stats, 0, 256 * 4, stream);
        hipMemsetAsync(gmax, 0, (size_t)NG * FD * 4, stream);

        // P = hbf @ BcatT[l]^T  -> bf16 [N][512]
        gemm_bb_kernel<<<dim3(8, MB), 256, 0, stream>>>(
            hbf, BcatT + (size_t)l * 512 * 128, Pbf, N_NODES, 512);

        msg5_kernel<<<N_EDGES / 64, 256, 0, stream>>>(
            Pbf, eabf, WecatT + (size_t)l * 256 * 64, bcat + (size_t)l * 256,
            srcS, dstS, agg);

        bn_stats_kernel<<<512, 256, 0, stream>>>(agg, stats);
        bn_update_kernel<<<(N_NODES + 1) / 2, 256, 0, stream>>>(
            h, hbf, agg, stats, bn_g + l * FD, bn_b + l * FD, batch, gmax);
        gf_acc_kernel<<<(NG * FD) / 256, 256, 0, stream>>>(gf, gmax);
    }

    head_y_kernel<<<NG, 128, 0, stream>>>(gf, w1, b1, y);
    head_stats_kernel<<<1, 128, 0, stream>>>(y, hstat);
    head_out_kernel<<<NG, 128, 0, stream>>>(y, hstat, bng, bnb, w2, b2, (float*)d_out);
}

// Round 6
// 1893.797 us; speedup vs baseline: 3.2825x; 1.1930x over previous
//
#include <hip/hip_runtime.h>
#include <hip/hip_bf16.h>

#define N_NODES 50000
#define N_EDGES 800000
#define FIN 92
#define FD 128
#define DE 50
#define NL 3
#define NG 256
#define MPAD 130

typedef short short8 __attribute__((ext_vector_type(8)));
typedef float f32x4 __attribute__((ext_vector_type(4)));

__device__ __forceinline__ short f2bf(float f) {
    unsigned u = __builtin_bit_cast(unsigned, f);
    unsigned r = (u + 0x7FFFu + ((u >> 16) & 1u)) >> 16;
    return (short)r;
}
__device__ __forceinline__ float bf2f(unsigned short b) {
    unsigned u = ((unsigned)b) << 16;
    return __builtin_bit_cast(float, u);
}

// stored-pos p (within a 128 segment) -> true feature
__device__ __forceinline__ int posFeat(int p) {
    return ((p >> 2) & 7) * 16 + ((p >> 5) << 2) + (p & 3);
}

// ---------------- fp32-input bf16-MFMA GEMM (embedding only) ----------------
template<int KPAD, int RELU, int OUTBF>
__global__ __launch_bounds__(256) void gemm_kernel(
    const float* __restrict__ A, const float* __restrict__ B,
    void* __restrict__ Cout, int M, int K, int Nc)
{
    __shared__ short Alds[64][KPAD + 8];
    __shared__ short Blds[64][KPAD + 8];   // holds B^T tile: [n][k]
    const int tid = threadIdx.x;
    const int m0 = blockIdx.y * 64;
    const int n0 = blockIdx.x * 64;

    for (int i = tid; i < 64 * KPAD; i += 256) {
        int r = i / KPAD, k = i - r * KPAD;
        int row = m0 + r;
        float v = (row < M && k < K) ? A[(size_t)row * K + k] : 0.f;
        Alds[r][k] = f2bf(v);
    }
    for (int i = tid; i < 64 * KPAD; i += 256) {
        int n = i & 63, k = i >> 6;
        float v = (k < K) ? B[(size_t)k * Nc + n0 + n] : 0.f;
        Blds[n][k] = f2bf(v);
    }
    __syncthreads();

    const int wv = tid >> 6, lane = tid & 63;
    const int lr = lane & 15, lk = (lane >> 4) * 8;
    f32x4 acc[4];
#pragma unroll
    for (int i = 0; i < 4; ++i) acc[i] = (f32x4)0.f;

    for (int k0 = 0; k0 < KPAD; k0 += 32) {
        short8 a = *(const short8*)&Alds[wv * 16 + lr][k0 + lk];
#pragma unroll
        for (int nf = 0; nf < 4; ++nf) {
            short8 b = *(const short8*)&Blds[nf * 16 + lr][k0 + lk];
            acc[nf] = __builtin_amdgcn_mfma_f32_16x16x32_bf16(a, b, acc[nf], 0, 0, 0);
        }
    }
#pragma unroll
    for (int nf = 0; nf < 4; ++nf) {
#pragma unroll
        for (int r = 0; r < 4; ++r) {
            int row = m0 + wv * 16 + (lane >> 4) * 4 + r;
            int col = n0 + nf * 16 + lr;
            if (row < M) {
                float v = acc[nf][r];
                if (RELU) v = fmaxf(v, 0.f);
                if (OUTBF) ((unsigned short*)Cout)[(size_t)row * Nc + col] = (unsigned short)f2bf(v);
                else       ((float*)Cout)[(size_t)row * Nc + col] = v;
            }
        }
    }
}

// ---------------- all-bf16 GEMM for P (+fp32 bias in epilogue) ----------------
__global__ __launch_bounds__(256) void gemm_bb_kernel(
    const unsigned short* __restrict__ Abf, const unsigned short* __restrict__ Bt,
    const float* __restrict__ bias,
    unsigned short* __restrict__ Cout, int M, int Nc)
{
    __shared__ short Alds[64][136];
    __shared__ short Blds[64][136];
    const int tid = threadIdx.x;
    const int m0 = blockIdx.y * 64;
    const int n0 = blockIdx.x * 64;

    for (int i = tid; i < 1024; i += 256) {   // 64 rows x 16 segs of 8 shorts
        int r = i >> 4, seg = i & 15;
        int row = m0 + r;
        short8 va = (row < M) ? *(const short8*)&Abf[(size_t)row * 128 + seg * 8] : (short8)0;
        *(short8*)&Alds[r][seg * 8] = va;
        *(short8*)&Blds[r][seg * 8] = *(const short8*)&Bt[(size_t)(n0 + r) * 128 + seg * 8];
    }
    __syncthreads();

    const int wv = tid >> 6, lane = tid & 63;
    const int lr = lane & 15, lk = (lane >> 4) * 8;
    f32x4 acc[4];
#pragma unroll
    for (int i = 0; i < 4; ++i) acc[i] = (f32x4)0.f;

#pragma unroll
    for (int k0 = 0; k0 < 128; k0 += 32) {
        short8 a = *(const short8*)&Alds[wv * 16 + lr][k0 + lk];
#pragma unroll
        for (int nf = 0; nf < 4; ++nf) {
            short8 b = *(const short8*)&Blds[nf * 16 + lr][k0 + lk];
            acc[nf] = __builtin_amdgcn_mfma_f32_16x16x32_bf16(a, b, acc[nf], 0, 0, 0);
        }
    }
#pragma unroll
    for (int nf = 0; nf < 4; ++nf) {
#pragma unroll
        for (int r = 0; r < 4; ++r) {
            int row = m0 + wv * 16 + (lane >> 4) * 4 + r;
            int col = n0 + nf * 16 + lr;
            if (row < M)
                Cout[(size_t)row * Nc + col] = (unsigned short)f2bf(acc[nf][r] + bias[col]);
        }
    }
}

// -------- build col-PERMUTED bf16 node-proj weights BcatT[l][512][128] + bias bcatF[l][512] --
// stored col n = seg*128 + p holds true feature seg*128 + posFeat(p)
__global__ __launch_bounds__(256) void build_bcatT_kernel(
    const float* __restrict__ wf, const float* __restrict__ wsw,
    const float* __restrict__ bfb, const float* __restrict__ bsb,
    unsigned short* __restrict__ BcatT, float* __restrict__ bcatF)
{
    int i = blockIdx.x * 256 + threadIdx.x;
    if (i < NL * 512 * 128) {
        int l = i / (512 * 128);
        int r = i - l * 512 * 128;
        int n = r >> 7, k = r & 127;
        int seg = n >> 7, p = n & 127;
        int nf_ = seg * 128 + posFeat(p);
        const float* Wm = (nf_ < 256) ? wf : wsw;
        int jj = nf_ & 255;
        int krow = (jj < 128) ? k : (128 + k);
        int col = jj & 127;
        BcatT[i] = (unsigned short)f2bf(Wm[((size_t)l * 306 + krow) * FD + col]);
    }
    if (i < NL * 512) {
        int l = i >> 9, n = i & 511;
        int seg = n >> 7, p = n & 127;
        float v = 0.f;
        if (seg == 0) v = bfb[l * FD + posFeat(p)];
        else if (seg == 2) v = bsb[l * FD + posFeat(p)];
        bcatF[i] = v;
    }
}

// -------- build transposed bf16 edge-proj weights WecatT[l][256][64] (rows = true features) --
__global__ __launch_bounds__(256) void build_wecat_kernel(
    const float* __restrict__ wf, const float* __restrict__ wsw,
    unsigned short* __restrict__ WecatT)
{
    int i = blockIdx.x * 256 + threadIdx.x;
    if (i >= NL * 256 * 64) return;
    int l = i / (256 * 64);
    int r = i - l * 256 * 64;
    int col = r >> 6, k = r & 63;
    float v = 0.f;
    if (k < DE) {
        const float* W = (col < 128) ? wf : wsw;
        v = W[((size_t)l * 306 + 256 + k) * FD + (col & 127)];
    }
    WecatT[i] = (unsigned short)f2bf(v);
}

// -------- h fp32 -> bf16 mirror --------
__global__ __launch_bounds__(256) void h2bf_kernel(
    const float* __restrict__ h, unsigned short* __restrict__ hbf)
{
    int i = blockIdx.x * 256 + threadIdx.x;
    if (i >= N_NODES * FD / 4) return;
    f32x4 v = *(const f32x4*)&h[i * 4];
    unsigned short o[4];
#pragma unroll
    for (int j = 0; j < 4; ++j) o[j] = (unsigned short)f2bf(v[j]);
    *(unsigned long long*)&hbf[i * 4] = *(unsigned long long*)o;
}

// ================= dst-sorted edge permutation (counting sort) =================
__global__ __launch_bounds__(256) void hist_kernel(
    const int* __restrict__ dstIdx, int* __restrict__ counts)
{
    int e = blockIdx.x * 256 + threadIdx.x;
    if (e < N_EDGES) atomicAdd(&counts[dstIdx[e]], 1);
}

__global__ __launch_bounds__(1024) void scan_kernel(
    const int* __restrict__ counts, int* __restrict__ cursor)
{
    __shared__ int part[1024];
    const int t = threadIdx.x;
    const int CH = 49;  // 1024*49 >= 50000
    const int base = t * CH;
    int s = 0;
    for (int i = 0; i < CH; ++i) {
        int idx = base + i;
        if (idx < N_NODES) s += counts[idx];
    }
    part[t] = s;
    __syncthreads();
    int v = s;
    for (int off = 1; off < 1024; off <<= 1) {
        int add = (t >= off) ? part[t - off] : 0;
        __syncthreads();
        v += add;
        part[t] = v;
        __syncthreads();
    }
    int pre = (t == 0) ? 0 : part[t - 1];
    for (int i = 0; i < CH; ++i) {
        int idx = base + i;
        if (idx < N_NODES) {
            cursor[idx] = pre;
            pre += counts[idx];
        }
    }
}

__global__ __launch_bounds__(256) void scatter_kernel(
    const int* __restrict__ eidx, int* __restrict__ cursor,
    int* __restrict__ perm, int* __restrict__ srcS, int* __restrict__ dstS)
{
    int e = blockIdx.x * 256 + threadIdx.x;
    if (e >= N_EDGES) return;
    int d = eidx[N_EDGES + e];
    int pos = atomicAdd(&cursor[d], 1);
    perm[pos] = e;
    srcS[pos] = eidx[e];
    dstS[pos] = d;
}

// -------- edge_attr -> bf16 padded [E][64], gathered into dst-sorted order --------
__global__ __launch_bounds__(256) void ea2bf_kernel(
    const float* __restrict__ ea, const int* __restrict__ perm,
    unsigned short* __restrict__ out)
{
    int i = blockIdx.x * 256 + threadIdx.x;
    if (i >= N_EDGES * 64) return;
    int e = i >> 6, k = i & 63;
    int pe = perm[e];
    out[i] = (k < DE) ? (unsigned short)f2bf(ea[(size_t)pe * DE + k]) : 0;
}

// ===== fused MFMA message kernel, operand-swapped: D[feature][edge] =====
// Each lane owns ONE edge (e = e0 + w*16 + (lane&15)); acc[nf][r] = feature nf*16+hi*4+r.
// P stored col-permuted so a lane's 32 values per segment are CONTIGUOUS (4x short8).
// Phase 2: LDS segment-sum over the dst-sorted window; interior runs -> plain store.
__global__ __launch_bounds__(256) void msg6_kernel(
    const unsigned short* __restrict__ Pbf,     // [N][512] bf16, col-permuted per 128-seg
    const unsigned short* __restrict__ eabf,    // [E][64] bf16, dst-sorted
    const unsigned short* __restrict__ WecatT,  // [256][64] bf16 (layer offset applied)
    const int* __restrict__ srcS, const int* __restrict__ dstS,
    float* __restrict__ agg)
{
    __shared__ float mlds[64][MPAD];
    __shared__ int dlds[66];
    const int tid = threadIdx.x;
    const int e0 = blockIdx.x * 64;

    if (tid < 66) {
        int ge = e0 - 1 + tid;
        int v;
        if (ge < 0) v = -1;
        else if (ge >= N_EDGES) v = -2;
        else v = dstS[ge];
        dlds[tid] = v;
    }

    const int w = tid >> 6, lane = tid & 63;
    const int lr = lane & 15, hi = lane >> 4;
    const int e = e0 + w * 16 + lr;          // this lane's edge
    const int eloc = w * 16 + lr;

    const int d = dstS[e], s = srcS[e];
    const unsigned short* pdrow = Pbf + (size_t)d * 512 + hi * 32;
    const unsigned short* psrow = Pbf + (size_t)s * 512 + hi * 32;
    short8 pdf[4], psf[4], pds[4], pss[4];
#pragma unroll
    for (int i = 0; i < 4; ++i) {
        pdf[i] = *(const short8*)(pdrow + i * 8);          // dstF seg
        psf[i] = *(const short8*)(psrow + 128 + i * 8);    // srcF seg
        pds[i] = *(const short8*)(pdrow + 256 + i * 8);    // dstS seg
        pss[i] = *(const short8*)(psrow + 384 + i * 8);    // srcS seg
    }

    f32x4 acc[16];
#pragma unroll
    for (int i = 0; i < 16; ++i) acc[i] = (f32x4)0.f;

    const size_t brow = (size_t)e * 64;
#pragma unroll
    for (int k0 = 0; k0 < 64; k0 += 32) {
        short8 b = *(const short8*)&eabf[brow + k0 + hi * 8];
#pragma unroll
        for (int nf = 0; nf < 16; ++nf) {
            short8 a = *(const short8*)&WecatT[(size_t)(nf * 16 + lr) * 64 + k0 + hi * 8];
            acc[nf] = __builtin_amdgcn_mfma_f32_16x16x32_bf16(a, b, acc[nf], 0, 0, 0);
        }
    }

#pragma unroll
    for (int nf = 0; nf < 8; ++nf) {
        f32x4 m;
#pragma unroll
        for (int r = 0; r < 4; ++r) {
            const int q = nf * 4 + r;
            float pf = acc[nf][r]     + bf2f((unsigned short)pdf[q >> 3][q & 7])
                                      + bf2f((unsigned short)psf[q >> 3][q & 7]);
            float pv = acc[nf + 8][r] + bf2f((unsigned short)pds[q >> 3][q & 7])
                                      + bf2f((unsigned short)pss[q >> 3][q & 7]);
            float sig = 1.f / (1.f + __expf(-pf));
            float t = __expf(-fabsf(pv));
            float sp = fmaxf(pv, 0.f) + __logf(1.f + t);
            m[r] = sig * sp;
        }
        *(f32x4*)&mlds[eloc][hi * 32 + nf * 4] = m;
    }
    __syncthreads();

    if (tid < 128) {
        const int t = tid;
        const int fcol = posFeat(t);    // unpermute on the agg write
        bool startsInside = (dlds[1] != dlds[0]);
        float run = 0.f;
        for (int ee = 0; ee < 64; ++ee) {
            run += mlds[ee][t];
            int de = dlds[ee + 1];
            int dnext = dlds[ee + 2];
            if (de != dnext) {   // run ends here (uniform branch across threads)
                if (startsInside) agg[(size_t)de * FD + fcol] = run;
                else unsafeAtomicAdd(&agg[(size_t)de * FD + fcol], run);
                run = 0.f;
                startsInside = true;
            }
        }
        if (run != 0.f)
            unsafeAtomicAdd(&agg[(size_t)dlds[64] * FD + fcol], run);
    }
}

// -------- BatchNorm stats over N rows --------
__global__ __launch_bounds__(256) void bn_stats_kernel(
    const float* __restrict__ agg, float* __restrict__ stats)
{
    const int tid = threadIdx.x;
    const int f = tid & 127;
    float s = 0.f, sq = 0.f;
    for (int row = blockIdx.x * 2 + (tid >> 7); row < N_NODES; row += gridDim.x * 2) {
        float v = agg[(size_t)row * FD + f];
        s += v; sq += v * v;
    }
    unsafeAtomicAdd(&stats[f], s);
    unsafeAtomicAdd(&stats[128 + f], sq);
}

// -------- h = relu(h + BN(agg)); write fp32 + bf16; atomicMax per-graph --------
__global__ __launch_bounds__(256) void bn_update_kernel(
    float* __restrict__ h, unsigned short* __restrict__ hbf,
    const float* __restrict__ agg,
    const float* __restrict__ stats, const float* __restrict__ g,
    const float* __restrict__ b, const int* __restrict__ batch,
    float* __restrict__ gmax)
{
    const int tid = threadIdx.x;
    const int row = blockIdx.x * 2 + (tid >> 7);
    if (row >= N_NODES) return;
    const int f = tid & 127;
    const float inv = 1.f / (float)N_NODES;
    float mu = stats[f] * inv;
    float var = stats[128 + f] * inv - mu * mu;
    float rs = rsqrtf(var + 1e-5f);
    size_t idx = (size_t)row * FD + f;
    float v = h[idx] + (agg[idx] - mu) * rs * g[f] + b[f];
    v = fmaxf(v, 0.f);
    h[idx] = v;
    hbf[idx] = (unsigned short)f2bf(v);
    atomicMax((unsigned*)&gmax[batch[row] * FD + f], __float_as_uint(v));
}

__global__ __launch_bounds__(256) void gf_acc_kernel(float* __restrict__ gf, const float* __restrict__ gmax)
{
    int i = blockIdx.x * 256 + threadIdx.x;
    gf[i] += gmax[i];
}

// -------- head --------
__global__ __launch_bounds__(128) void head_y_kernel(
    const float* __restrict__ gf, const float* __restrict__ w1,
    const float* __restrict__ b1, float* __restrict__ y)
{
    __shared__ float row[128];
    int g = blockIdx.x, j = threadIdx.x;
    row[j] = gf[g * FD + j];
    __syncthreads();
    float acc = b1[j];
    for (int k = 0; k < FD; ++k) acc = fmaf(row[k], w1[k * FD + j], acc);
    y[g * FD + j] = acc;
}

__global__ __launch_bounds__(128) void head_stats_kernel(
    const float* __restrict__ y, float* __restrict__ hstat)
{
    int f = threadIdx.x;
    float s = 0.f, sq = 0.f;
    for (int g = 0; g < NG; ++g) { float v = y[g * FD + f]; s += v; sq += v * v; }
    float mu = s / (float)NG;
    float var = sq / (float)NG - mu * mu;
    hstat[f] = mu;
    hstat[128 + f] = rsqrtf(var + 1e-5f);
}

__global__ __launch_bounds__(128) void head_out_kernel(
    const float* __restrict__ y, const float* __restrict__ hstat,
    const float* __restrict__ bng, const float* __restrict__ bnb,
    const float* __restrict__ w2, const float* __restrict__ b2,
    float* __restrict__ out)
{
    __shared__ float part[2];
    int g = blockIdx.x, f = threadIdx.x;
    float v = (y[g * FD + f] - hstat[f]) * hstat[128 + f] * bng[f] + bnb[f];
    v = fmaxf(v, 0.f) * w2[f];
    for (int o = 32; o > 0; o >>= 1) v += __shfl_down(v, o);
    if ((f & 63) == 0) part[f >> 6] = v;
    __syncthreads();
    if (f == 0) out[g] = part[0] + part[1] + b2[0];
}

extern "C" void kernel_launch(void* const* d_in, const int* in_sizes, int n_in,
                              void* d_out, int out_size, void* d_ws, size_t ws_size,
                              hipStream_t stream)
{
    const float* x        = (const float*)d_in[0];
    const float* edge_attr= (const float*)d_in[1];
    const float* w_emb0   = (const float*)d_in[2];
    const float* w_emb1   = (const float*)d_in[3];
    const float* wf       = (const float*)d_in[4];
    const float* bf       = (const float*)d_in[5];
    const float* wsw      = (const float*)d_in[6];
    const float* bs       = (const float*)d_in[7];
    const float* bn_g     = (const float*)d_in[8];
    const float* bn_b     = (const float*)d_in[9];
    const float* w1       = (const float*)d_in[10];
    const float* b1       = (const float*)d_in[11];
    const float* bng      = (const float*)d_in[12];
    const float* bnb      = (const float*)d_in[13];
    const float* w2       = (const float*)d_in[14];
    const float* b2       = (const float*)d_in[15];
    const int*   eidx     = (const int*)d_in[16];   // [2][E]: row0=src, row1=dst
    const int*   batch    = (const int*)d_in[17];

    char* base = (char*)d_ws;
    size_t off = 0;
    auto alloc = [&](size_t bytes) -> void* {
        void* p = base + off;
        off += (bytes + 255) & ~(size_t)255;
        return p;
    };
    float*          h      = (float*)alloc((size_t)N_NODES * FD * 4);
    unsigned short* hbf    = (unsigned short*)alloc((size_t)N_NODES * FD * 2);
    unsigned short* Pbf    = (unsigned short*)alloc((size_t)N_NODES * 512 * 2);
    float*          agg    = (float*)alloc((size_t)N_NODES * FD * 4);   // also embed tmp + sort scratch
    unsigned short* BcatT  = (unsigned short*)alloc((size_t)NL * 512 * 128 * 2);
    unsigned short* WecatT = (unsigned short*)alloc((size_t)NL * 256 * 64 * 2);
    float*          bcatF  = (float*)alloc((size_t)NL * 512 * 4);
    unsigned short* eabf   = (unsigned short*)alloc((size_t)N_EDGES * 64 * 2);
    int*            srcS   = (int*)alloc((size_t)N_EDGES * 4);
    int*            dstS   = (int*)alloc((size_t)N_EDGES * 4);
    float*          stats  = (float*)alloc(256 * 4);
    float*          gmax   = (float*)alloc((size_t)NG * FD * 4);
    float*          gf     = (float*)alloc((size_t)NG * FD * 4);
    float*          y      = (float*)alloc((size_t)NG * FD * 4);
    float*          hstat  = (float*)alloc(256 * 4);

    // sort scratch overlaid on agg (dead until layer loop; all sort users complete first)
    int* perm   = (int*)agg;               // [E]
    int* counts = perm + N_EDGES;          // [N]
    int* cursor = counts + N_NODES;        // [N]

    const int MB = (N_NODES + 63) / 64;  // 782

    // ---- dst-sort the edges (once, reused across layers) ----
    hipMemsetAsync(counts, 0, (size_t)N_NODES * 4, stream);
    hist_kernel<<<(N_EDGES + 255) / 256, 256, 0, stream>>>(eidx + N_EDGES, counts);
    scan_kernel<<<1, 1024, 0, stream>>>(counts, cursor);
    scatter_kernel<<<(N_EDGES + 255) / 256, 256, 0, stream>>>(eidx, cursor, perm, srcS, dstS);
    ea2bf_kernel<<<(N_EDGES * 64) / 256, 256, 0, stream>>>(edge_attr, perm, eabf);

    build_bcatT_kernel<<<(NL * 512 * 128 + 255) / 256, 256, 0, stream>>>(wf, wsw, bf, bs, BcatT, bcatF);
    build_wecat_kernel<<<(NL * 256 * 64 + 255) / 256, 256, 0, stream>>>(wf, wsw, WecatT);

    // embedding MLP: t0 = relu(x@w_emb0); h = t0@w_emb1   (t0 uses agg buffer, after sort done)
    gemm_kernel<96, 1, 0><<<dim3(2, MB), 256, 0, stream>>>(x, w_emb0, agg, N_NODES, FIN, FD);
    gemm_kernel<128, 0, 0><<<dim3(2, MB), 256, 0, stream>>>(agg, w_emb1, h, N_NODES, FD, FD);
    h2bf_kernel<<<(N_NODES * FD / 4 + 255) / 256, 256, 0, stream>>>(h, hbf);

    hipMemsetAsync(gf, 0, (size_t)NG * FD * 4, stream);

    for (int l = 0; l < NL; ++l) {
        hipMemsetAsync(agg, 0, (size_t)N_NODES * FD * 4, stream);
        hipMemsetAsync(stats, 0, 256 * 4, stream);
        hipMemsetAsync(gmax, 0, (size_t)NG * FD * 4, stream);

        // P = hbf @ BcatT[l]^T + bcatF[l]  -> bf16 [N][512], col-permuted
        gemm_bb_kernel<<<dim3(8, MB), 256, 0, stream>>>(
            hbf, BcatT + (size_t)l * 512 * 128, bcatF + (size_t)l * 512, Pbf, N_NODES, 512);

        msg6_kernel<<<N_EDGES / 64, 256, 0, stream>>>(
            Pbf, eabf, WecatT + (size_t)l * 256 * 64, srcS, dstS, agg);

        bn_stats_kernel<<<512, 256, 0, stream>>>(agg, stats);
        bn_update_kernel<<<(N_NODES + 1) / 2, 256, 0, stream>>>(
            h, hbf, agg, stats, bn_g + l * FD, bn_b + l * FD, batch, gmax);
        gf_acc_kernel<<<(NG * FD) / 256, 256, 0, stream>>>(gf, gmax);
    }

    head_y_kernel<<<NG, 128, 0, stream>>>(gf, w1, b1, y);
    head_stats_kernel<<<1, 128, 0, stream>>>(y, hstat);
    head_out_kernel<<<NG, 128, 0, stream>>>(y, hstat, bng, bnb, w2, b2, (float*)d_out);
}

// Round 7
// 1630.581 us; speedup vs baseline: 3.8124x; 1.1614x over previous
//
#include <hip/hip_runtime.h>
#include <hip/hip_bf16.h>

#define N_NODES 50000
#define N_EDGES 800000
#define FIN 92
#define FD 128
#define DE 50
#define NL 3
#define NG 256
#define MPAD 130

typedef short short8 __attribute__((ext_vector_type(8)));
typedef float f32x4 __attribute__((ext_vector_type(4)));

__device__ __forceinline__ short f2bf(float f) {
    unsigned u = __builtin_bit_cast(unsigned, f);
    unsigned r = (u + 0x7FFFu + ((u >> 16) & 1u)) >> 16;
    return (short)r;
}
__device__ __forceinline__ float bf2f(unsigned short b) {
    unsigned u = ((unsigned)b) << 16;
    return __builtin_bit_cast(float, u);
}

// stored-pos p (within a 128 segment) -> true feature
__device__ __forceinline__ int posFeat(int p) {
    return ((p >> 2) & 7) * 16 + ((p >> 5) << 2) + (p & 3);
}

// ------- fp32-input bf16-MFMA GEMM (embedding only). OUTMODE: 0=f32, 1=bf16, 2=both -------
template<int KPAD, int RELU, int OUTMODE>
__global__ __launch_bounds__(256) void gemm_kernel(
    const float* __restrict__ A, const float* __restrict__ B,
    void* __restrict__ Cout, void* __restrict__ Cout2, int M, int K, int Nc)
{
    __shared__ short Alds[64][KPAD + 8];
    __shared__ short Blds[64][KPAD + 8];   // holds B^T tile: [n][k]
    const int tid = threadIdx.x;
    const int m0 = blockIdx.y * 64;
    const int n0 = blockIdx.x * 64;

    for (int i = tid; i < 64 * KPAD; i += 256) {
        int r = i / KPAD, k = i - r * KPAD;
        int row = m0 + r;
        float v = (row < M && k < K) ? A[(size_t)row * K + k] : 0.f;
        Alds[r][k] = f2bf(v);
    }
    for (int i = tid; i < 64 * KPAD; i += 256) {
        int n = i & 63, k = i >> 6;
        float v = (k < K) ? B[(size_t)k * Nc + n0 + n] : 0.f;
        Blds[n][k] = f2bf(v);
    }
    __syncthreads();

    const int wv = tid >> 6, lane = tid & 63;
    const int lr = lane & 15, lk = (lane >> 4) * 8;
    f32x4 acc[4];
#pragma unroll
    for (int i = 0; i < 4; ++i) acc[i] = (f32x4)0.f;

    for (int k0 = 0; k0 < KPAD; k0 += 32) {
        short8 a = *(const short8*)&Alds[wv * 16 + lr][k0 + lk];
#pragma unroll
        for (int nf = 0; nf < 4; ++nf) {
            short8 b = *(const short8*)&Blds[nf * 16 + lr][k0 + lk];
            acc[nf] = __builtin_amdgcn_mfma_f32_16x16x32_bf16(a, b, acc[nf], 0, 0, 0);
        }
    }
#pragma unroll
    for (int nf = 0; nf < 4; ++nf) {
#pragma unroll
        for (int r = 0; r < 4; ++r) {
            int row = m0 + wv * 16 + (lane >> 4) * 4 + r;
            int col = n0 + nf * 16 + lr;
            if (row < M) {
                float v = acc[nf][r];
                if (RELU) v = fmaxf(v, 0.f);
                if (OUTMODE == 1) ((unsigned short*)Cout)[(size_t)row * Nc + col] = (unsigned short)f2bf(v);
                else              ((float*)Cout)[(size_t)row * Nc + col] = v;
                if (OUTMODE == 2) ((unsigned short*)Cout2)[(size_t)row * Nc + col] = (unsigned short)f2bf(v);
            }
        }
    }
}

// ---------------- all-bf16 GEMM for P (+fp32 bias in epilogue) ----------------
__global__ __launch_bounds__(256) void gemm_bb_kernel(
    const unsigned short* __restrict__ Abf, const unsigned short* __restrict__ Bt,
    const float* __restrict__ bias,
    unsigned short* __restrict__ Cout, int M, int Nc)
{
    __shared__ short Alds[64][136];
    __shared__ short Blds[64][136];
    const int tid = threadIdx.x;
    const int m0 = blockIdx.y * 64;
    const int n0 = blockIdx.x * 64;

    for (int i = tid; i < 1024; i += 256) {   // 64 rows x 16 segs of 8 shorts
        int r = i >> 4, seg = i & 15;
        int row = m0 + r;
        short8 va = (row < M) ? *(const short8*)&Abf[(size_t)row * 128 + seg * 8] : (short8)0;
        *(short8*)&Alds[r][seg * 8] = va;
        *(short8*)&Blds[r][seg * 8] = *(const short8*)&Bt[(size_t)(n0 + r) * 128 + seg * 8];
    }
    __syncthreads();

    const int wv = tid >> 6, lane = tid & 63;
    const int lr = lane & 15, lk = (lane >> 4) * 8;
    f32x4 acc[4];
#pragma unroll
    for (int i = 0; i < 4; ++i) acc[i] = (f32x4)0.f;

#pragma unroll
    for (int k0 = 0; k0 < 128; k0 += 32) {
        short8 a = *(const short8*)&Alds[wv * 16 + lr][k0 + lk];
#pragma unroll
        for (int nf = 0; nf < 4; ++nf) {
            short8 b = *(const short8*)&Blds[nf * 16 + lr][k0 + lk];
            acc[nf] = __builtin_amdgcn_mfma_f32_16x16x32_bf16(a, b, acc[nf], 0, 0, 0);
        }
    }
#pragma unroll
    for (int nf = 0; nf < 4; ++nf) {
#pragma unroll
        for (int r = 0; r < 4; ++r) {
            int row = m0 + wv * 16 + (lane >> 4) * 4 + r;
            int col = n0 + nf * 16 + lr;
            if (row < M)
                Cout[(size_t)row * Nc + col] = (unsigned short)f2bf(acc[nf][r] + bias[col]);
        }
    }
}

// -------- build col-PERMUTED bf16 node-proj weights BcatT[l][512][128] + bias bcatF[l][512] --
__global__ __launch_bounds__(256) void build_bcatT_kernel(
    const float* __restrict__ wf, const float* __restrict__ wsw,
    const float* __restrict__ bfb, const float* __restrict__ bsb,
    unsigned short* __restrict__ BcatT, float* __restrict__ bcatF)
{
    int i = blockIdx.x * 256 + threadIdx.x;
    if (i < NL * 512 * 128) {
        int l = i / (512 * 128);
        int r = i - l * 512 * 128;
        int n = r >> 7, k = r & 127;
        int seg = n >> 7, p = n & 127;
        int nf_ = seg * 128 + posFeat(p);
        const float* Wm = (nf_ < 256) ? wf : wsw;
        int jj = nf_ & 255;
        int krow = (jj < 128) ? k : (128 + k);
        int col = jj & 127;
        BcatT[i] = (unsigned short)f2bf(Wm[((size_t)l * 306 + krow) * FD + col]);
    }
    if (i < NL * 512) {
        int l = i >> 9, n = i & 511;
        int seg = n >> 7, p = n & 127;
        float v = 0.f;
        if (seg == 0) v = bfb[l * FD + posFeat(p)];
        else if (seg == 2) v = bsb[l * FD + posFeat(p)];
        bcatF[i] = v;
    }
}

// -------- build transposed bf16 edge-proj weights WecatT[l][256][64] --------
__global__ __launch_bounds__(256) void build_wecat_kernel(
    const float* __restrict__ wf, const float* __restrict__ wsw,
    unsigned short* __restrict__ WecatT)
{
    int i = blockIdx.x * 256 + threadIdx.x;
    if (i >= NL * 256 * 64) return;
    int l = i / (256 * 64);
    int r = i - l * 256 * 64;
    int col = r >> 6, k = r & 63;
    float v = 0.f;
    if (k < DE) {
        const float* W = (col < 128) ? wf : wsw;
        v = W[((size_t)l * 306 + 256 + k) * FD + (col & 127)];
    }
    WecatT[i] = (unsigned short)f2bf(v);
}

// ================= dst-sorted edge permutation (counting sort) =================
__global__ __launch_bounds__(256) void hist_kernel(
    const int* __restrict__ dstIdx, int* __restrict__ counts)
{
    int e = blockIdx.x * 256 + threadIdx.x;
    if (e < N_EDGES) atomicAdd(&counts[dstIdx[e]], 1);
}

__global__ __launch_bounds__(1024) void scan_kernel(
    const int* __restrict__ counts, int* __restrict__ cursor)
{
    __shared__ int part[1024];
    const int t = threadIdx.x;
    const int CH = 49;  // 1024*49 >= 50000
    const int base = t * CH;
    int s = 0;
    for (int i = 0; i < CH; ++i) {
        int idx = base + i;
        if (idx < N_NODES) s += counts[idx];
    }
    part[t] = s;
    __syncthreads();
    int v = s;
    for (int off = 1; off < 1024; off <<= 1) {
        int add = (t >= off) ? part[t - off] : 0;
        __syncthreads();
        v += add;
        part[t] = v;
        __syncthreads();
    }
    int pre = (t == 0) ? 0 : part[t - 1];
    for (int i = 0; i < CH; ++i) {
        int idx = base + i;
        if (idx < N_NODES) {
            cursor[idx] = pre;
            pre += counts[idx];
        }
    }
}

__global__ __launch_bounds__(256) void scatter_kernel(
    const int* __restrict__ eidx, int* __restrict__ cursor,
    int* __restrict__ perm, int* __restrict__ srcS, int* __restrict__ dstS)
{
    int e = blockIdx.x * 256 + threadIdx.x;
    if (e >= N_EDGES) return;
    int d = eidx[N_EDGES + e];
    int pos = atomicAdd(&cursor[d], 1);
    perm[pos] = e;
    srcS[pos] = eidx[e];
    dstS[pos] = d;
}

// -------- edge_attr -> bf16 padded [E][64], gathered into dst-sorted order --------
__global__ __launch_bounds__(256) void ea2bf_kernel(
    const float* __restrict__ ea, const int* __restrict__ perm,
    unsigned short* __restrict__ out)
{
    int i = blockIdx.x * 256 + threadIdx.x;
    if (i >= N_EDGES * 64) return;
    int e = i >> 6, k = i & 63;
    int pe = perm[e];
    out[i] = (k < DE) ? (unsigned short)f2bf(ea[(size_t)pe * DE + k]) : 0;
}

// ===== msg7: operand-swapped MFMA message kernel, 32-edge blocks, all-thread segment-sum ====
// 128 threads / 2 waves; lane owns one edge e = e0 + (tid>>6)*16 + (lane&15).
// acc[nf][r] = feature nf*16 + hi*4 + r of its edge (filter nf<8, soft nf>=8).
// Phase 2: 128 threads (one col each) walk the 32-edge window; interior runs -> plain store.
__global__ __launch_bounds__(128) void msg7_kernel(
    const unsigned short* __restrict__ Pbf,     // [N][512] bf16, col-permuted per 128-seg
    const unsigned short* __restrict__ eabf,    // [E][64] bf16, dst-sorted
    const unsigned short* __restrict__ WecatT,  // [256][64] bf16 (layer offset applied)
    const int* __restrict__ srcS, const int* __restrict__ dstS,
    float* __restrict__ agg)
{
    __shared__ float mlds[32][MPAD];
    __shared__ int dlds[34];
    const int tid = threadIdx.x;
    const int e0 = blockIdx.x * 32;

    if (tid < 34) {
        int ge = e0 - 1 + tid;
        int v;
        if (ge < 0) v = -1;
        else if (ge >= N_EDGES) v = -2;
        else v = dstS[ge];
        dlds[tid] = v;
    }

    const int w = tid >> 6, lane = tid & 63;
    const int lr = lane & 15, hi = lane >> 4;
    const int e = e0 + w * 16 + lr;          // this lane's edge
    const int eloc = w * 16 + lr;

    const int d = dstS[e], s = srcS[e];
    const unsigned short* pdrow = Pbf + (size_t)d * 512 + hi * 32;
    const unsigned short* psrow = Pbf + (size_t)s * 512 + hi * 32;
    short8 pdf[4], psf[4], pds[4], pss[4];
#pragma unroll
    for (int i = 0; i < 4; ++i) {
        pdf[i] = *(const short8*)(pdrow + i * 8);          // dstF seg
        psf[i] = *(const short8*)(psrow + 128 + i * 8);    // srcF seg
        pds[i] = *(const short8*)(pdrow + 256 + i * 8);    // dstS seg
        pss[i] = *(const short8*)(psrow + 384 + i * 8);    // srcS seg
    }

    f32x4 acc[16];
#pragma unroll
    for (int i = 0; i < 16; ++i) acc[i] = (f32x4)0.f;

    const size_t brow = (size_t)e * 64;
#pragma unroll
    for (int k0 = 0; k0 < 64; k0 += 32) {
        short8 b = *(const short8*)&eabf[brow + k0 + hi * 8];
#pragma unroll
        for (int nf = 0; nf < 16; ++nf) {
            short8 a = *(const short8*)&WecatT[(size_t)(nf * 16 + lr) * 64 + k0 + hi * 8];
            acc[nf] = __builtin_amdgcn_mfma_f32_16x16x32_bf16(a, b, acc[nf], 0, 0, 0);
        }
    }

#pragma unroll
    for (int nf = 0; nf < 8; ++nf) {
        f32x4 m;
#pragma unroll
        for (int r = 0; r < 4; ++r) {
            const int q = nf * 4 + r;
            float pf = acc[nf][r]     + bf2f((unsigned short)pdf[q >> 3][q & 7])
                                      + bf2f((unsigned short)psf[q >> 3][q & 7]);
            float pv = acc[nf + 8][r] + bf2f((unsigned short)pds[q >> 3][q & 7])
                                      + bf2f((unsigned short)pss[q >> 3][q & 7]);
            float sig = 1.f / (1.f + __expf(-pf));
            float t = __expf(-fabsf(pv));
            float sp = fmaxf(pv, 0.f) + __logf(1.f + t);
            m[r] = sig * sp;
        }
        *(f32x4*)&mlds[eloc][hi * 32 + nf * 4] = m;
    }
    __syncthreads();

    {
        const int c = tid;                // col 0..127
        const int fcol = posFeat(c);      // unpermute on the agg write
        bool startsInside = (dlds[1] != dlds[0]);
        float run = 0.f;
#pragma unroll 4
        for (int ee = 0; ee < 32; ++ee) {
            run += mlds[ee][c];
            int de = dlds[ee + 1];
            int dnext = dlds[ee + 2];
            if (de != dnext) {   // run ends here (uniform branch across threads)
                if (startsInside) agg[(size_t)de * FD + fcol] = run;
                else unsafeAtomicAdd(&agg[(size_t)de * FD + fcol], run);
                run = 0.f;
                startsInside = true;
            }
        }
        if (run != 0.f)
            unsafeAtomicAdd(&agg[(size_t)dlds[32] * FD + fcol], run);
    }
}

// -------- BatchNorm stats over N rows (LDS pair-reduce, then one atomic per col) --------
__global__ __launch_bounds__(256) void bn_stats_kernel(
    const float* __restrict__ agg, float* __restrict__ stats)
{
    __shared__ float sl[256], sql[256];
    const int tid = threadIdx.x;
    const int f = tid & 127;
    float s = 0.f, sq = 0.f;
    for (int row = blockIdx.x * 2 + (tid >> 7); row < N_NODES; row += gridDim.x * 2) {
        float v = agg[(size_t)row * FD + f];
        s += v; sq += v * v;
    }
    sl[tid] = s; sql[tid] = sq;
    __syncthreads();
    if (tid < 128) {
        unsafeAtomicAdd(&stats[f], sl[tid] + sl[tid + 128]);
        unsafeAtomicAdd(&stats[128 + f], sql[tid] + sql[tid + 128]);
    }
}

// -------- h = relu(h + BN(agg)); write fp32 + bf16; atomicMax per-graph --------
__global__ __launch_bounds__(256) void bn_update_kernel(
    float* __restrict__ h, unsigned short* __restrict__ hbf,
    const float* __restrict__ agg,
    const float* __restrict__ stats, const float* __restrict__ g,
    const float* __restrict__ b, const int* __restrict__ batch,
    float* __restrict__ gmax)
{
    const int tid = threadIdx.x;
    const int row = blockIdx.x * 2 + (tid >> 7);
    if (row >= N_NODES) return;
    const int f = tid & 127;
    const float inv = 1.f / (float)N_NODES;
    float mu = stats[f] * inv;
    float var = stats[128 + f] * inv - mu * mu;
    float rs = rsqrtf(var + 1e-5f);
    size_t idx = (size_t)row * FD + f;
    float v = h[idx] + (agg[idx] - mu) * rs * g[f] + b[f];
    v = fmaxf(v, 0.f);
    h[idx] = v;
    hbf[idx] = (unsigned short)f2bf(v);
    atomicMax((unsigned*)&gmax[batch[row] * FD + f], __float_as_uint(v));
}

__global__ __launch_bounds__(256) void gf_acc_kernel(float* __restrict__ gf, const float* __restrict__ gmax)
{
    int i = blockIdx.x * 256 + threadIdx.x;
    gf[i] += gmax[i];
}

// -------- head --------
__global__ __launch_bounds__(128) void head_y_kernel(
    const float* __restrict__ gf, const float* __restrict__ w1,
    const float* __restrict__ b1, float* __restrict__ y)
{
    __shared__ float row[128];
    int g = blockIdx.x, j = threadIdx.x;
    row[j] = gf[g * FD + j];
    __syncthreads();
    float acc = b1[j];
    for (int k = 0; k < FD; ++k) acc = fmaf(row[k], w1[k * FD + j], acc);
    y[g * FD + j] = acc;
}

__global__ __launch_bounds__(128) void head_stats_kernel(
    const float* __restrict__ y, float* __restrict__ hstat)
{
    int f = threadIdx.x;
    float s = 0.f, sq = 0.f;
    for (int g = 0; g < NG; ++g) { float v = y[g * FD + f]; s += v; sq += v * v; }
    float mu = s / (float)NG;
    float var = sq / (float)NG - mu * mu;
    hstat[f] = mu;
    hstat[128 + f] = rsqrtf(var + 1e-5f);
}

__global__ __launch_bounds__(128) void head_out_kernel(
    const float* __restrict__ y, const float* __restrict__ hstat,
    const float* __restrict__ bng, const float* __restrict__ bnb,
    const float* __restrict__ w2, const float* __restrict__ b2,
    float* __restrict__ out)
{
    __shared__ float part[2];
    int g = blockIdx.x, f = threadIdx.x;
    float v = (y[g * FD + f] - hstat[f]) * hstat[128 + f] * bng[f] + bnb[f];
    v = fmaxf(v, 0.f) * w2[f];
    for (int o = 32; o > 0; o >>= 1) v += __shfl_down(v, o);
    if ((f & 63) == 0) part[f >> 6] = v;
    __syncthreads();
    if (f == 0) out[g] = part[0] + part[1] + b2[0];
}

extern "C" void kernel_launch(void* const* d_in, const int* in_sizes, int n_in,
                              void* d_out, int out_size, void* d_ws, size_t ws_size,
                              hipStream_t stream)
{
    const float* x        = (const float*)d_in[0];
    const float* edge_attr= (const float*)d_in[1];
    const float* w_emb0   = (const float*)d_in[2];
    const float* w_emb1   = (const float*)d_in[3];
    const float* wf       = (const float*)d_in[4];
    const float* bf       = (const float*)d_in[5];
    const float* wsw      = (const float*)d_in[6];
    const float* bs       = (const float*)d_in[7];
    const float* bn_g     = (const float*)d_in[8];
    const float* bn_b     = (const float*)d_in[9];
    const float* w1       = (const float*)d_in[10];
    const float* b1       = (const float*)d_in[11];
    const float* bng      = (const float*)d_in[12];
    const float* bnb      = (const float*)d_in[13];
    const float* w2       = (const float*)d_in[14];
    const float* b2       = (const float*)d_in[15];
    const int*   eidx     = (const int*)d_in[16];   // [2][E]: row0=src, row1=dst
    const int*   batch    = (const int*)d_in[17];

    char* base = (char*)d_ws;
    size_t off = 0;
    auto alloc = [&](size_t bytes) -> void* {
        void* p = base + off;
        off += (bytes + 255) & ~(size_t)255;
        return p;
    };
    float*          h      = (float*)alloc((size_t)N_NODES * FD * 4);
    unsigned short* hbf    = (unsigned short*)alloc((size_t)N_NODES * FD * 2);
    unsigned short* Pbf    = (unsigned short*)alloc((size_t)N_NODES * 512 * 2);
    float*          agg    = (float*)alloc((size_t)N_NODES * FD * 4);   // also embed tmp + sort scratch
    unsigned short* BcatT  = (unsigned short*)alloc((size_t)NL * 512 * 128 * 2);
    unsigned short* WecatT = (unsigned short*)alloc((size_t)NL * 256 * 64 * 2);
    float*          bcatF  = (float*)alloc((size_t)NL * 512 * 4);
    unsigned short* eabf   = (unsigned short*)alloc((size_t)N_EDGES * 64 * 2);
    int*            srcS   = (int*)alloc((size_t)N_EDGES * 4);
    int*            dstS   = (int*)alloc((size_t)N_EDGES * 4);
    float*          stats  = (float*)alloc(256 * 4);
    float*          gmax   = (float*)alloc((size_t)NG * FD * 4);
    float*          gf     = (float*)alloc((size_t)NG * FD * 4);
    float*          y      = (float*)alloc((size_t)NG * FD * 4);
    float*          hstat  = (float*)alloc(256 * 4);

    // sort scratch overlaid on agg (dead until layer loop; all sort users complete first)
    int* perm   = (int*)agg;               // [E]
    int* counts = perm + N_EDGES;          // [N]
    int* cursor = counts + N_NODES;        // [N]

    const int MB = (N_NODES + 63) / 64;  // 782

    // ---- dst-sort the edges (once, reused across layers) ----
    hipMemsetAsync(counts, 0, (size_t)N_NODES * 4, stream);
    hist_kernel<<<(N_EDGES + 255) / 256, 256, 0, stream>>>(eidx + N_EDGES, counts);
    scan_kernel<<<1, 1024, 0, stream>>>(counts, cursor);
    scatter_kernel<<<(N_EDGES + 255) / 256, 256, 0, stream>>>(eidx, cursor, perm, srcS, dstS);
    ea2bf_kernel<<<(N_EDGES * 64) / 256, 256, 0, stream>>>(edge_attr, perm, eabf);

    build_bcatT_kernel<<<(NL * 512 * 128 + 255) / 256, 256, 0, stream>>>(wf, wsw, bf, bs, BcatT, bcatF);
    build_wecat_kernel<<<(NL * 256 * 64 + 255) / 256, 256, 0, stream>>>(wf, wsw, WecatT);

    // embedding MLP: t0 = relu(x@w_emb0); h = t0@w_emb1 (writes fp32 h + bf16 hbf fused)
    gemm_kernel<96, 1, 0><<<dim3(2, MB), 256, 0, stream>>>(x, w_emb0, agg, nullptr, N_NODES, FIN, FD);
    gemm_kernel<128, 0, 2><<<dim3(2, MB), 256, 0, stream>>>(agg, w_emb1, h, hbf, N_NODES, FD, FD);

    hipMemsetAsync(gf, 0, (size_t)NG * FD * 4, stream);

    for (int l = 0; l < NL; ++l) {
        hipMemsetAsync(agg, 0, (size_t)N_NODES * FD * 4, stream);
        hipMemsetAsync(stats, 0, 256 * 4, stream);
        hipMemsetAsync(gmax, 0, (size_t)NG * FD * 4, stream);

        // P = hbf @ BcatT[l]^T + bcatF[l]  -> bf16 [N][512], col-permuted
        gemm_bb_kernel<<<dim3(8, MB), 256, 0, stream>>>(
            hbf, BcatT + (size_t)l * 512 * 128, bcatF + (size_t)l * 512, Pbf, N_NODES, 512);

        msg7_kernel<<<N_EDGES / 32, 128, 0, stream>>>(
            Pbf, eabf, WecatT + (size_t)l * 256 * 64, srcS, dstS, agg);

        bn_stats_kernel<<<256, 256, 0, stream>>>(agg, stats);
        bn_update_kernel<<<(N_NODES + 1) / 2, 256, 0, stream>>>(
            h, hbf, agg, stats, bn_g + l * FD, bn_b + l * FD, batch, gmax);
        gf_acc_kernel<<<(NG * FD) / 256, 256, 0, stream>>>(gf, gmax);
    }

    head_y_kernel<<<NG, 128, 0, stream>>>(gf, w1, b1, y);
    head_stats_kernel<<<1, 128, 0, stream>>>(y, hstat);
    head_out_kernel<<<NG, 128, 0, stream>>>(y, hstat, bng, bnb, w2, b2, (float*)d_out);
}